// Round 25
// baseline (194.652 us; speedup 1.0000x reference)
//
#include <hip/hip_runtime.h>
#include <hip/hip_bf16.h>

// N=8192, K=16, CIN=64, C=256, S=8, C/S=32 ; float tensors are float32.
#define INV_N  (1.0f/8192.0f)
#define INV_NK (1.0f/131072.0f)

typedef __attribute__((ext_vector_type(8))) short bf16x8;
typedef __attribute__((ext_vector_type(4))) float f32x4;
typedef unsigned short u16;

__device__ __forceinline__ u16 f2b(float f) {   // f32 -> bf16 RNE
  unsigned u = __float_as_uint(f);
  return (u16)((u + 0x7FFFu + ((u >> 16) & 1u)) >> 16);
}
__device__ __forceinline__ float b2f(u16 u) {
  return __uint_as_float(((unsigned)u) << 16);
}

__device__ __forceinline__ float bn_ap(float v, const float* st, int C, int ch,
                                       float inv, float g, float b) {
  float m = st[ch] * inv;
  float var = st[C + ch] * inv - m * m;
  return (v - m) * rsqrtf(var + 1e-5f) * g + b;
}

// ---------------------------------------------------------------- prep
__launch_bounds__(256)
__global__ void prep_k(const float* __restrict__ p, const int* __restrict__ o,
                       const float* __restrict__ Ww1,
                       float4* __restrict__ pp, u16* __restrict__ Ww1t,
                       float* __restrict__ st, float* __restrict__ out) {
  int b = blockIdx.x, t = threadIdx.x;
  int e = b*256 + t;
  if (b < 16) st[b*256 + t] = 0.f;
  if (e < 24576) out[e] = p[e];
  if (e == 0) out[24576 + 2097152] = (float)o[0];
  if (e < 8192) {
    float x = p[e*3+0], y = p[e*3+1], z = p[e*3+2];
    pp[e] = make_float4(x, y, z, (x*x + y*y) + z*z);
  }
  if (b >= 88) {
    int q = (b - 88)*1024 + t*4;
#pragma unroll
    for (int ii = 0; ii < 4; ++ii) {
      int e2 = q + ii;
      int k = e2 >> 5, n = e2 & 31;
      Ww1t[n*256 + k] = f2b(Ww1[e2]);
    }
  }
}

// ---------------------------------------------------------------- generic partial-sum reduce
template<int ROWS, int SPLIT>
__launch_bounds__(256)
__global__ void red_k(const float* __restrict__ part, float* __restrict__ outp,
                      int width) {
  int ncg = width >> 6;
  int cg = blockIdx.x % ncg, sp = blockIdx.x / ncg;
  int lane = threadIdx.x & 63, chunk = threadIdx.x >> 6;
  int c = cg*64 + lane;
  constexpr int R  = ROWS / SPLIT;
  constexpr int RC = R / 4;
  float s = 0.f;
  int i0 = sp*R + chunk*RC;
#pragma unroll 4
  for (int i = i0; i < i0 + RC; ++i) s += part[(size_t)i*width + c];
  __shared__ float red[4][64];
  red[chunk][lane] = s;
  __syncthreads();
  if (threadIdx.x < 64) {
    float v = red[0][lane] + red[1][lane] + red[2][lane] + red[3][lane];
    if (SPLIT == 1) outp[c] = v;
    else atomicAdd(&outp[c], v);
  }
}

// ---------------------------------------------------------------- KNN v7: 1 query/wave, 16 KB chunks
__device__ __forceinline__ void knn_dev(char* smem, const float4* __restrict__ pp,
                                        int* __restrict__ idxo, int kb) {
  float4* buf = (float4*)smem;                 // 1024 float4 = 16 KB
  int t = threadIdx.x;
  int wave = t >> 6, lane = t & 63;
  int q = kb*4 + wave;
  float4 qv = pp[q];
  const float BIG = __uint_as_float(0x7F7FFFFFu);
  float d[3];
#pragma unroll
  for (int s = 0; s < 3; ++s) d[s] = BIG;
  for (int ch = 0; ch < 8; ++ch) {
#pragma unroll
    for (int s = 0; s < 4; ++s)
      buf[s*256 + t] = pp[ch*1024 + s*256 + t];
    __syncthreads();
#pragma unroll 4
    for (int it = 0; it < 16; ++it) {
      int jl = it*64 + lane;
      float4 c = buf[jl];
      int j = ch*1024 + jl;
      float dot = qv.x*c.x + (qv.y*c.y + qv.z*c.z);
      float d2 = __fmaf_rn(-2.0f, dot, qv.w + c.w);
      float pk = __uint_as_float((__float_as_uint(d2) & 0xFFFFE000u) | (unsigned)j);
      d[2] = fminf(fmaxf(d[1], pk), d[2]);
      d[1] = fminf(fmaxf(d[0], pk), d[1]);
      d[0] = fminf(d[0], pk);
    }
    __syncthreads();
  }
  for (int r = 0; r < 16; ++r) {
    float bd = d[0];
#pragma unroll
    for (int m = 1; m < 64; m <<= 1)
      bd = fminf(bd, __shfl_xor(bd, m));
    if (lane == 0) idxo[q*16 + r] = (int)(__float_as_uint(bd) & 0x1FFFu);
    if (d[0] == bd) { d[0] = d[1]; d[1] = d[2]; d[2] = BIG; }
  }
}

// ---------------------------------------------------------------- MFMA GEMM device body (20480 B smem)
template<typename TA, typename TO, bool BNA, bool STATS>
__device__ __forceinline__ void mfgemm_dev(char* smem,
    const TA* __restrict__ A, const float* __restrict__ st,
    const float* __restrict__ g, const float* __restrict__ bb, float inv_cnt,
    const float* __restrict__ W, TO* __restrict__ out,
    float* __restrict__ stout, int KA, int NOUT, int bm, int bn_) {
  short (*As)[72] = (short(*)[72])smem;
  short (*Bt)[72] = (short(*)[72])(smem + 9216);
  float* lscl = (float*)(smem + 18432);
  float* lsft = (float*)(smem + 19456);
  int t = threadIdx.x;
  int m0 = bm * 64, n0 = bn_ * 64;
  if (BNA) {
    for (int e = t; e < KA; e += 256) {
      float m = st[e] * inv_cnt;
      float var = st[KA + e] * inv_cnt - m*m;
      float sc = rsqrtf(var + 1e-5f) * g[e];
      lscl[e] = sc; lsft[e] = bb[e] - m*sc;
    }
    __syncthreads();
  }
  const f32x4 zero = {0.f, 0.f, 0.f, 0.f};
  f32x4 acc[2][2] = {{zero, zero}, {zero, zero}};
  int wv = t >> 6, l = t & 63;
  int wm = wv & 1, wn = wv >> 1;
  int lr = l & 15, lk = (l >> 4) * 8;
  int ra = t >> 4, qa = t & 15;
  int bn = t & 63, bkc = t >> 6;
  for (int k0 = 0; k0 < KA; k0 += 64) {
#pragma unroll
    for (int rp = 0; rp < 4; ++rp) {
      int r = rp*16 + ra;
      float vv[4];
      if constexpr (sizeof(TA) == 4) {
        float4 av = *(const float4*)((const float*)A + (size_t)(m0 + r)*KA + k0 + qa*4);
        vv[0] = av.x; vv[1] = av.y; vv[2] = av.z; vv[3] = av.w;
      } else {
        short4 av = *(const short4*)((const u16*)A + (size_t)(m0 + r)*KA + k0 + qa*4);
#pragma unroll
        for (int jj = 0; jj < 4; ++jj) vv[jj] = b2f(((u16*)&av)[jj]);
      }
      short4 s;
#pragma unroll
      for (int jj = 0; jj < 4; ++jj) {
        float v = vv[jj];
        if (BNA) { int ch = k0 + qa*4 + jj; v = fmaxf(fmaf(v, lscl[ch], lsft[ch]), 0.f); }
        ((u16*)&s)[jj] = f2b(v);
      }
      *(short4*)&As[r][qa*4] = s;
    }
    {
      float v[16];
#pragma unroll
      for (int j2 = 0; j2 < 16; ++j2)
        v[j2] = W[(size_t)(k0 + bkc*16 + j2)*NOUT + n0 + bn];
      bf16x8 w0, w1v;
#pragma unroll
      for (int j2 = 0; j2 < 8; ++j2) {
        w0[j2]  = (short)f2b(v[j2]);
        w1v[j2] = (short)f2b(v[8 + j2]);
      }
      *(bf16x8*)&Bt[bn][bkc*16]     = w0;
      *(bf16x8*)&Bt[bn][bkc*16 + 8] = w1v;
    }
    __syncthreads();
#pragma unroll
    for (int fk = 0; fk < 2; ++fk) {
      bf16x8 a0 = *(const bf16x8*)&As[wm*32 +      lr][fk*32 + lk];
      bf16x8 a1 = *(const bf16x8*)&As[wm*32 + 16 + lr][fk*32 + lk];
      bf16x8 b0 = *(const bf16x8*)&Bt[wn*32 +      lr][fk*32 + lk];
      bf16x8 b1 = *(const bf16x8*)&Bt[wn*32 + 16 + lr][fk*32 + lk];
      acc[0][0] = __builtin_amdgcn_mfma_f32_16x16x32_bf16(a0, b0, acc[0][0], 0, 0, 0);
      acc[0][1] = __builtin_amdgcn_mfma_f32_16x16x32_bf16(a0, b1, acc[0][1], 0, 0, 0);
      acc[1][0] = __builtin_amdgcn_mfma_f32_16x16x32_bf16(a1, b0, acc[1][0], 0, 0, 0);
      acc[1][1] = __builtin_amdgcn_mfma_f32_16x16x32_bf16(a1, b1, acc[1][1], 0, 0, 0);
    }
    __syncthreads();
  }
#pragma unroll
  for (int fn = 0; fn < 2; ++fn) {
    int col = n0 + wn*32 + fn*16 + lr;
    float s1 = 0.f, s2 = 0.f;
#pragma unroll
    for (int fm = 0; fm < 2; ++fm) {
#pragma unroll
      for (int r = 0; r < 4; ++r) {
        int row = m0 + wm*32 + fm*16 + (l >> 4)*4 + r;
        float v = acc[fm][fn][r];
        if constexpr (sizeof(TO) == 4) out[(size_t)row*NOUT + col] = v;
        else                           out[(size_t)row*NOUT + col] = f2b(v);
        if (STATS) { s1 += v; s2 += v*v; }
      }
    }
    if (STATS) {
      s1 += __shfl_xor(s1, 16); s1 += __shfl_xor(s1, 32);
      s2 += __shfl_xor(s2, 16); s2 += __shfl_xor(s2, 32);
      if (l < 16) {
        atomicAdd(&stout[col], s1);
        atomicAdd(&stout[NOUT + col], s2);
      }
    }
  }
}

// ---------------------------------------------------------------- p_r helpers
__device__ __forceinline__ void comp_pr1(const float* p, int i, int j,
                                         const float* Wp1, const float* bp1,
                                         float pr1[3]) {
  float rx = p[j*3+0] - p[i*3+0];
  float ry = p[j*3+1] - p[i*3+1];
  float rz = p[j*3+2] - p[i*3+2];
#pragma unroll
  for (int c = 0; c < 3; ++c)
    pr1[c] = rx*Wp1[c] + ry*Wp1[3+c] + rz*Wp1[6+c] + bp1[c];
}

__device__ __forceinline__ void comp_prv(const float* p, int i, int j,
                                         const float* Wp1, const float* bp1,
                                         const float* gp, const float* bpp,
                                         const float* sp, float o3[3]) {
  float pr1[3];
  comp_pr1(p, i, j, Wp1, bp1, pr1);
#pragma unroll
  for (int c = 0; c < 3; ++c)
    o3[c] = fmaxf(bn_ap(pr1[c], sp, 3, c, INV_NK, gp[c], bpp[c]), 0.0f);
}

// ---------------------------------------------------------------- prstats standalone
__launch_bounds__(256)
__global__ void prstats_k(const float* __restrict__ p, const int* __restrict__ idx,
                          const float* Wp1, const float* bp1, float* __restrict__ sp) {
  float s[3] = {0,0,0}, s2[3] = {0,0,0};
  for (int it = 0; it < 4; ++it) {
    int e = blockIdx.x*1024 + it*256 + threadIdx.x;
    int i = e >> 4;
    int j = idx[e] & 8191;
    float pr1[3];
    comp_pr1(p, i, j, Wp1, bp1, pr1);
#pragma unroll
    for (int c = 0; c < 3; ++c) { s[c] += pr1[c]; s2[c] += pr1[c]*pr1[c]; }
  }
#pragma unroll
  for (int m = 1; m < 64; m <<= 1) {
#pragma unroll
    for (int c = 0; c < 3; ++c) {
      s[c]  += __shfl_xor(s[c],  m);
      s2[c] += __shfl_xor(s2[c], m);
    }
  }
  __shared__ float red[4][6];
  int wv = threadIdx.x >> 6, lane = threadIdx.x & 63;
  if (lane == 0) {
#pragma unroll
    for (int c = 0; c < 3; ++c) { red[wv][c] = s[c]; red[wv][3+c] = s2[c]; }
  }
  __syncthreads();
  if (threadIdx.x < 6) {
    float v = red[0][threadIdx.x] + red[1][threadIdx.x] +
              red[2][threadIdx.x] + red[3][threadIdx.x];
    atomicAdd(&sp[threadIdx.x], v);
  }
}

// ---------------------------------------------------------------- packed: mfgemm2 (512) || knn-full (2048)
__launch_bounds__(256)
__global__ void gemm2knn_k(const u16* __restrict__ t0, const float* __restrict__ st0,
                           const float* __restrict__ g_pa, const float* __restrict__ b_pa,
                           const float* __restrict__ W1, u16* __restrict__ t1,
                           float* __restrict__ st1,
                           const float4* __restrict__ pp, int* __restrict__ idxo) {
  extern __shared__ char smem[];
  int b = blockIdx.x;
  if (b < 512)
    mfgemm_dev<u16, u16, true, true>(smem, t0, st0, g_pa, b_pa, INV_N,
                                     W1, t1, st1, 256, 256, b & 127, b >> 7);
  else
    knn_dev(smem, pp, idxo, b - 512);        // kb 0..2047 -> all 8192 queries
}

// ---------------------------------------------------------------- standalone mfgemm wrapper (gemm1 + W3 passes)
template<typename TA, typename TO, bool BNA, bool STATS>
__launch_bounds__(256)
__global__ void mfgemm_k(const TA* __restrict__ A, const float* __restrict__ st,
                         const float* __restrict__ g, const float* __restrict__ bb,
                         float inv_cnt,
                         const float* __restrict__ W, TO* __restrict__ out,
                         float* __restrict__ stout, int KA, int NOUT) {
  extern __shared__ char smem[];
  mfgemm_dev<TA, TO, BNA, STATS>(smem, A, st, g, bb, inv_cnt, W, out, stout,
                                 KA, NOUT, blockIdx.x, blockIdx.y);
}

// ---------------------------------------------------------------- fused Q/K/V MFMA (bf16 in/out, static smem)
__launch_bounds__(256)
__global__ void qkv_k(const u16* __restrict__ t1, const float* __restrict__ st,
                      const float* __restrict__ g1, const float* __restrict__ b1,
                      const float* __restrict__ Wq, const float* __restrict__ bq,
                      const float* __restrict__ Wk, const float* __restrict__ bk,
                      const float* __restrict__ Wv, const float* __restrict__ bv,
                      u16* __restrict__ xq, u16* __restrict__ xk, u16* __restrict__ xv) {
  __shared__ short As[64][72];
  __shared__ short Bt[3][64][72];
  __shared__ float lscl[256], lsft[256];
  int t = threadIdx.x;
  int m0 = blockIdx.x * 64, n0 = blockIdx.y * 64;
  {
    int e = t;
    float m = st[e] * INV_N;
    float var = st[256 + e] * INV_N - m*m;
    float sc = rsqrtf(var + 1e-5f) * g1[e];
    lscl[e] = sc; lsft[e] = b1[e] - m*sc;
  }
  __syncthreads();
  const f32x4 zero = {0.f, 0.f, 0.f, 0.f};
  f32x4 acc[3][2][2];
#pragma unroll
  for (int w = 0; w < 3; ++w)
#pragma unroll
    for (int i = 0; i < 2; ++i)
#pragma unroll
      for (int j = 0; j < 2; ++j) acc[w][i][j] = zero;
  int wv = t >> 6, l = t & 63;
  int wm = wv & 1, wn = wv >> 1;
  int lr = l & 15, lk = (l >> 4) * 8;
  int ra = t >> 4, qa = t & 15;
  int bn = t & 63, bkc = t >> 6;
  const float* Ws[3] = {Wq, Wk, Wv};
  for (int k0 = 0; k0 < 256; k0 += 64) {
#pragma unroll
    for (int rp = 0; rp < 4; ++rp) {
      int r = rp*16 + ra;
      short4 av = *(const short4*)(t1 + (size_t)(m0 + r)*256 + k0 + qa*4);
      short4 s;
#pragma unroll
      for (int jj = 0; jj < 4; ++jj) {
        int ch = k0 + qa*4 + jj;
        float v = fmaxf(fmaf(b2f(((u16*)&av)[jj]), lscl[ch], lsft[ch]), 0.f);
        ((u16*)&s)[jj] = f2b(v);
      }
      *(short4*)&As[r][qa*4] = s;
    }
#pragma unroll
    for (int w = 0; w < 3; ++w) {
      float v[16];
#pragma unroll
      for (int j2 = 0; j2 < 16; ++j2)
        v[j2] = Ws[w][(size_t)(k0 + bkc*16 + j2)*256 + n0 + bn];
      bf16x8 w0, w1v;
#pragma unroll
      for (int j2 = 0; j2 < 8; ++j2) {
        w0[j2]  = (short)f2b(v[j2]);
        w1v[j2] = (short)f2b(v[8 + j2]);
      }
      *(bf16x8*)&Bt[w][bn][bkc*16]     = w0;
      *(bf16x8*)&Bt[w][bn][bkc*16 + 8] = w1v;
    }
    __syncthreads();
#pragma unroll
    for (int fk = 0; fk < 2; ++fk) {
      bf16x8 a0 = *(const bf16x8*)&As[wm*32 +      lr][fk*32 + lk];
      bf16x8 a1 = *(const bf16x8*)&As[wm*32 + 16 + lr][fk*32 + lk];
#pragma unroll
      for (int w = 0; w < 3; ++w) {
        bf16x8 b0 = *(const bf16x8*)&Bt[w][wn*32 +      lr][fk*32 + lk];
        bf16x8 b1 = *(const bf16x8*)&Bt[w][wn*32 + 16 + lr][fk*32 + lk];
        acc[w][0][0] = __builtin_amdgcn_mfma_f32_16x16x32_bf16(a0, b0, acc[w][0][0], 0, 0, 0);
        acc[w][0][1] = __builtin_amdgcn_mfma_f32_16x16x32_bf16(a0, b1, acc[w][0][1], 0, 0, 0);
        acc[w][1][0] = __builtin_amdgcn_mfma_f32_16x16x32_bf16(a1, b0, acc[w][1][0], 0, 0, 0);
        acc[w][1][1] = __builtin_amdgcn_mfma_f32_16x16x32_bf16(a1, b1, acc[w][1][1], 0, 0, 0);
      }
    }
    __syncthreads();
  }
  u16* outs[3] = {xq, xk, xv};
  const float* bs[3] = {bq, bk, bv};
#pragma unroll
  for (int w = 0; w < 3; ++w) {
#pragma unroll
    for (int fn = 0; fn < 2; ++fn) {
      int col = n0 + wn*32 + fn*16 + lr;
      float bvv = bs[w][col];
#pragma unroll
      for (int fm = 0; fm < 2; ++fm) {
#pragma unroll
        for (int r = 0; r < 4; ++r) {
          int row = m0 + wm*32 + fm*16 + (l >> 4)*4 + r;
          outs[w][(size_t)row*256 + col] = f2b(acc[w][fm][fn][r] + bvv);
        }
      }
    }
  }
}

// ---------------------------------------------------------------- y stats -> partials (bf16 in)
__launch_bounds__(256)
__global__ void stats256_k(const u16* __restrict__ X, float* __restrict__ psy) {
  int c = threadIdx.x;
  int r0 = blockIdx.x * 32;
  float s1 = 0.f, s2 = 0.f;
  for (int r = 0; r < 32; ++r) {
    float v = b2f(X[(size_t)(r0 + r)*256 + c]);
    s1 += v; s2 += v*v;
  }
  psy[(size_t)blockIdx.x*512 + c]       = s1;
  psy[(size_t)blockIdx.x*512 + 256 + c] = s2;
}

// ---------------------------------------------------------------- stats of w -> partials
__launch_bounds__(256)
__global__ void wstats_k(const u16* __restrict__ xk, const u16* __restrict__ xq,
                         const float* __restrict__ p, const int* __restrict__ idx,
                         const float* Wp1, const float* bp1, const float* gp, const float* bpp,
                         const float* sp, const float* __restrict__ Wp2, const float* bp2,
                         float* __restrict__ pws) {
  __shared__ float prv[8][16][4];
  __shared__ int   jidx[8][16];
  int base = blockIdx.x * 8;
  int t = threadIdx.x;
  if (t < 128) {
    int pt = t >> 4, k = t & 15;
    int j = idx[(base + pt)*16 + k] & 8191;
    jidx[pt][k] = j;
    float o3[3];
    comp_prv(p, base + pt, j, Wp1, bp1, gp, bpp, sp, o3);
    prv[pt][k][0] = o3[0]; prv[pt][k][1] = o3[1]; prv[pt][k][2] = o3[2];
  }
  __syncthreads();
  int c = t;
  float wp0 = Wp2[c], wp1v = Wp2[256+c], wp2v = Wp2[512+c];
  float bbv = bp2[c];
  float s1 = 0.f, s2 = 0.f;
  for (int pt = 0; pt < 8; ++pt) {
    int i = base + pt;
    float xqv = b2f(xq[(size_t)i*256 + c]);
    u16 kvals[16];
#pragma unroll
    for (int k = 0; k < 16; ++k)
      kvals[k] = xk[(size_t)jidx[pt][k]*256 + c];
#pragma unroll
    for (int k = 0; k < 16; ++k) {
      float pr = prv[pt][k][0]*wp0 + prv[pt][k][1]*wp1v + prv[pt][k][2]*wp2v + bbv;
      float wval = b2f(kvals[k]) - xqv + pr;
      s1 += wval; s2 += wval*wval;
    }
  }
  pws[(size_t)blockIdx.x*512 + c]       = s1;
  pws[(size_t)blockIdx.x*512 + 256 + c] = s2;
}

// ---------------------------------------------------------------- w1gemm: gather + partial-store stats
__launch_bounds__(256)
__global__ void w1gemm_k(const u16* __restrict__ xk, const u16* __restrict__ xq,
                         const float* __restrict__ p, const int* __restrict__ idx,
                         const float* Wp1, const float* bp1, const float* gp, const float* bpp,
                         const float* sp, const float* __restrict__ Wp2, const float* bp2,
                         const float* sw, const float* gw1, const float* bw1,
                         const u16* __restrict__ Ww1t, const float* bww1,
                         u16* __restrict__ w1, float* __restrict__ pw1) {
  __shared__ short sA[64][264];
  __shared__ float prv[64][3];
  __shared__ int   jrow[64];
  __shared__ float sred[256];
  int t = threadIdx.x;
  int base4 = blockIdx.x * 4;
  if (t < 64) {
    int grow = blockIdx.x*64 + t;
    int j = idx[grow] & 8191;
    jrow[t] = j;
    float o3[3];
    comp_prv(p, grow >> 4, j, Wp1, bp1, gp, bpp, sp, o3);
    prv[t][0] = o3[0]; prv[t][1] = o3[1]; prv[t][2] = o3[2];
  }
  __syncthreads();
  {
    int o = t & 31, rs = t >> 5;
    int ch0 = o*8;
    int jr[8];
#pragma unroll
    for (int ii = 0; ii < 8; ++ii) jr[ii] = jrow[ii*8 + rs];
    bf16x8 kvv[8], qvv[8];
#pragma unroll
    for (int ii = 0; ii < 8; ++ii) {
      int r = ii*8 + rs;
      kvv[ii] = *(const bf16x8*)(xk + (size_t)jr[ii]*256 + ch0);
      qvv[ii] = *(const bf16x8*)(xq + (size_t)(base4 + (r >> 4))*256 + ch0);
    }
    float sclv[8], sftv[8], w0v[8], w1vv[8], w2v[8], b2v[8];
#pragma unroll
    for (int h = 0; h < 2; ++h) {
      float4 swm = *(const float4*)(sw + ch0 + h*4);
      float4 sws = *(const float4*)(sw + 256 + ch0 + h*4);
      float4 g4  = *(const float4*)(gw1 + ch0 + h*4);
      float4 bb4 = *(const float4*)(bw1 + ch0 + h*4);
      float4 p0v = *(const float4*)(Wp2 + ch0 + h*4);
      float4 p1v = *(const float4*)(Wp2 + 256 + ch0 + h*4);
      float4 p2v = *(const float4*)(Wp2 + 512 + ch0 + h*4);
      float4 bp4 = *(const float4*)(bp2 + ch0 + h*4);
      float mv[4] = {swm.x, swm.y, swm.z, swm.w};
      float sv[4] = {sws.x, sws.y, sws.z, sws.w};
      float gv[4] = {g4.x, g4.y, g4.z, g4.w};
      float bv[4] = {bb4.x, bb4.y, bb4.z, bb4.w};
      float a0[4] = {p0v.x, p0v.y, p0v.z, p0v.w};
      float a1[4] = {p1v.x, p1v.y, p1v.z, p1v.w};
      float a2[4] = {p2v.x, p2v.y, p2v.z, p2v.w};
      float a3[4] = {bp4.x, bp4.y, bp4.z, bp4.w};
#pragma unroll
      for (int jj = 0; jj < 4; ++jj) {
        int e = h*4 + jj;
        float m = mv[jj]*INV_NK;
        float var = sv[jj]*INV_NK - m*m;
        float sc = rsqrtf(var + 1e-5f)*gv[jj];
        sclv[e] = sc; sftv[e] = bv[jj] - m*sc;
        w0v[e] = a0[jj]; w1vv[e] = a1[jj]; w2v[e] = a2[jj]; b2v[e] = a3[jj];
      }
    }
#pragma unroll
    for (int ii = 0; ii < 8; ++ii) {
      int r = ii*8 + rs;
      float p0 = prv[r][0], p1 = prv[r][1], p2 = prv[r][2];
      bf16x8 av;
#pragma unroll
      for (int e = 0; e < 8; ++e) {
        float v = b2f((u16)kvv[ii][e]) - b2f((u16)qvv[ii][e])
                + p0*w0v[e] + p1*w1vv[e] + p2*w2v[e] + b2v[e];
        v = fmaxf(fmaf(v, sclv[e], sftv[e]), 0.f);
        av[e] = (short)f2b(v);
      }
      *(bf16x8*)&sA[r][ch0] = av;
    }
  }
  __syncthreads();
  const f32x4 zero = {0.f,0.f,0.f,0.f};
  f32x4 acc[2] = {zero, zero};
  int wv = t >> 6, l = t & 63;
  int lr = l & 15, hi = l >> 4;
#pragma unroll
  for (int k0 = 0; k0 < 8; ++k0) {
    int kb = k0*32 + hi*8;
    bf16x8 a  = *(const bf16x8*)&sA[wv*16 + lr][kb];
    bf16x8 b0 = *(const bf16x8*)(Ww1t + (size_t)lr*256      + kb);
    bf16x8 b1 = *(const bf16x8*)(Ww1t + (size_t)(16+lr)*256 + kb);
    acc[0] = __builtin_amdgcn_mfma_f32_16x16x32_bf16(a, b0, acc[0], 0, 0, 0);
    acc[1] = __builtin_amdgcn_mfma_f32_16x16x32_bf16(a, b1, acc[1], 0, 0, 0);
  }
#pragma unroll
  for (int fn = 0; fn < 2; ++fn) {
    int col = fn*16 + lr;
    float bv = bww1[col];
    float s1 = 0.f, s2 = 0.f;
#pragma unroll
    for (int r = 0; r < 4; ++r) {
      int grow = blockIdx.x*64 + wv*16 + hi*4 + r;
      float v = acc[fn][r] + bv;
      w1[(size_t)grow*32 + col] = f2b(v);
      s1 += v; s2 += v*v;
    }
    s1 += __shfl_xor(s1, 16); s1 += __shfl_xor(s1, 32);
    s2 += __shfl_xor(s2, 16); s2 += __shfl_xor(s2, 32);
    if (l < 16) { sred[(wv*2+fn)*16 + lr] = s1; sred[128 + (wv*2+fn)*16 + lr] = s2; }
  }
  __syncthreads();
  if (t < 32) {
    float a = 0.f, b = 0.f;
#pragma unroll
    for (int w2 = 0; w2 < 4; ++w2) {
      a += sred[(w2*2 + (t >> 4))*16 + (t & 15)];
      b += sred[128 + (w2*2 + (t >> 4))*16 + (t & 15)];
    }
    pw1[(size_t)blockIdx.x*64 + t]      = a;
    pw1[(size_t)blockIdx.x*64 + 32 + t] = b;
  }
}

// ---------------------------------------------------------------- aggr (1 query/block, proven)
__launch_bounds__(256)
__global__ void aggr_k(const u16* __restrict__ w1, const float* sw1,
                       const float* gw2, const float* bw2,
                       const float* __restrict__ Ww2, const float* bww2,
                       const u16* __restrict__ xv,
                       const float* __restrict__ p, const int* __restrict__ idx,
                       const float* Wp1, const float* bp1, const float* gp, const float* bpp,
                       const float* sp, const float* __restrict__ Wp2, const float* bp2,
                       u16* __restrict__ y) {
  __shared__ float lw1[16][32];
  __shared__ float lW2[32][32];
  __shared__ float sw2[16][33];
  __shared__ float prv[16][4];
  __shared__ int   jidx[16];
  int i = blockIdx.x, t = threadIdx.x;
  for (int e = t; e < 1024; e += 256) lW2[e >> 5][e & 31] = Ww2[e];
  for (int e = t; e < 512; e += 256) {
    int c32 = e & 31;
    float v = b2f(w1[(size_t)i*512 + e]);
    v = fmaxf(bn_ap(v, sw1, 32, c32, INV_NK, gw2[c32], bw2[c32]), 0.0f);
    lw1[e >> 5][c32] = v;
  }
  if (t < 16) jidx[t] = idx[i*16 + t] & 8191;
  __syncthreads();
  if (t < 16) {
    float o3[3];
    comp_prv(p, i, jidx[t], Wp1, bp1, gp, bpp, sp, o3);
    prv[t][0] = o3[0]; prv[t][1] = o3[1]; prv[t][2] = o3[2];
  }
  for (int e = t; e < 512; e += 256) {
    int k = e >> 5, c32 = e & 31;
    float a = bww2[c32];
#pragma unroll
    for (int j = 0; j < 32; ++j) a += lw1[k][j] * lW2[j][c32];
    sw2[k][c32] = a;
  }
  __syncthreads();
  if (t < 32) {
    float mx = -3.0e38f;
#pragma unroll
    for (int k = 0; k < 16; ++k) mx = fmaxf(mx, sw2[k][t]);
    float s = 0.f;
#pragma unroll
    for (int k = 0; k < 16; ++k) { float e2 = expf(sw2[k][t] - mx); sw2[k][t] = e2; s += e2; }
    float r = 1.0f / s;
#pragma unroll
    for (int k = 0; k < 16; ++k) sw2[k][t] *= r;
  }
  __syncthreads();
  int c = t;
  float wp0 = Wp2[c], wp1v = Wp2[256+c], wp2v = Wp2[512+c];
  float bbv = bp2[c];
  int c32 = c & 31;
  float acc = 0.f;
#pragma unroll
  for (int k = 0; k < 16; ++k) {
    int j = jidx[k];
    float pr = prv[k][0]*wp0 + prv[k][1]*wp1v + prv[k][2]*wp2v + bbv;
    float xvv = b2f(xv[(size_t)j*256 + c]);
    acc += (xvv + pr) * sw2[k][c32];
  }
  y[(size_t)i*256 + c] = f2b(acc);
}

// ---------------------------------------------------------------- epilogue (bf16 in)
__launch_bounds__(256)
__global__ void final_k(const u16* __restrict__ t0, const float* s0,
                        const float* g0, const float* b0,
                        const u16* __restrict__ t3, const float* s3,
                        const float* g3, const float* b3,
                        float* __restrict__ out) {
  int i = blockIdx.x, c = threadIdx.x;
  size_t off = (size_t)i*256 + c;
  float h0 = fmaxf(bn_ap(b2f(t0[off]), s0, 256, c, INV_N, g0[c], b0[c]), 0.0f);
  float v3 = bn_ap(b2f(t3[off]), s3, 256, c, INV_N, g3[c], b3[c]);
  out[24576 + off] = fmaxf(v3 + h0, 0.0f);
}

// ---------------------------------------------------------------- launch
extern "C" void kernel_launch(void* const* d_in, const int* in_sizes, int n_in,
                              void* d_out, int out_size, void* d_ws, size_t ws_size,
                              hipStream_t stream) {
  (void)in_sizes; (void)n_in; (void)out_size; (void)ws_size;
  const float* p    = (const float*)d_in[0];
  const float* x    = (const float*)d_in[1];
  const int*   o    = (const int*)  d_in[2];
  const float* W_pa = (const float*)d_in[3];
  const float* g_pa = (const float*)d_in[4];
  const float* b_pa = (const float*)d_in[5];
  const float* W1   = (const float*)d_in[6];
  const float* g1   = (const float*)d_in[7];
  const float* b1   = (const float*)d_in[8];
  const float* Wq   = (const float*)d_in[9];
  const float* bq   = (const float*)d_in[10];
  const float* Wk   = (const float*)d_in[11];
  const float* bk   = (const float*)d_in[12];
  const float* Wv   = (const float*)d_in[13];
  const float* bv   = (const float*)d_in[14];
  const float* Wp1  = (const float*)d_in[15];
  const float* bp1  = (const float*)d_in[16];
  const float* gp   = (const float*)d_in[17];
  const float* bpp  = (const float*)d_in[18];
  const float* Wp2  = (const float*)d_in[19];
  const float* bp2  = (const float*)d_in[20];
  const float* gw1  = (const float*)d_in[21];
  const float* bw1  = (const float*)d_in[22];
  const float* Ww1  = (const float*)d_in[23];
  const float* bww1 = (const float*)d_in[24];
  const float* gw2  = (const float*)d_in[25];
  const float* bw2  = (const float*)d_in[26];
  const float* Ww2  = (const float*)d_in[27];
  const float* bww2 = (const float*)d_in[28];
  const float* g2   = (const float*)d_in[29];
  const float* b2   = (const float*)d_in[30];
  const float* W3   = (const float*)d_in[31];
  const float* g3   = (const float*)d_in[32];
  const float* b3   = (const float*)d_in[33];

  // workspace layout (~34 MB)
  char* ws = (char*)d_ws;
  u16*   t0  = (u16*)  (ws + 0);          // [8192,256] bf16 (live til final_k)
  u16*   t1  = (u16*)  (ws + 4194304);    // [8192,256] bf16 (later: y)
  u16*   xq  = (u16*)  (ws + 8388608);    // [8192,256] bf16 (later: t3)
  u16*   xk  = (u16*)  (ws + 12582912);   // [8192,256] bf16
  u16*   xv  = (u16*)  (ws + 16777216);   // [8192,256] bf16
  u16*   w1  = (u16*)  (ws + 20971520);   // [131072,32] bf16 (8 MB)
  int*   idx = (int*)  (ws + 29360128);   // [8192,16] i32
  float* st  = (float*)(ws + 29884416);   // stats block (16 KB)
  u16*   Ww1t= (u16*)  (ws + 29900800);   // [32][256] bf16 (16 KB)
  float* pw1 = (float*)(ws + 30408704);   // [2048][64] partials (512 KB)
  float* pws = (float*)(ws + 30932992);   // [1024][512] partials (2 MB)
  float* psy = (float*)(ws + 33030144);   // [256][512] partials (512 KB)
  u16*   y   = t1;                        // aggr output (t1 dead after qkv)
  u16*   t3  = xq;                        // aliases xq (dead after w1 stage)
  float4* pp = (float4*)(ws + 20971520);  // aliases w1 (knn finishes first)
  // st offsets: s0=0, s1=512, sw=1024, sy=1536, s3=2048, sw1=2560, sp=2624

  prep_k<<<96, 256, 0, stream>>>(p, o, Ww1, pp, Ww1t, st, (float*)d_out);

  // gemm1 standalone (small K=64 pass) ...
  mfgemm_k<float, u16, false, true><<<dim3(128, 4), 256, 20480, stream>>>(
      x, nullptr, nullptr, nullptr, 0.f, W_pa, t0, st + 0, 64, 256);

  // ... so the BIGGER gemm2 (K=256) hides under the full knn
  gemm2knn_k<<<2560, 256, 20480, stream>>>(t0, st + 0, g_pa, b_pa, W1, t1,
                                           st + 512, pp, idx);

  prstats_k<<<128, 256, 0, stream>>>(p, idx, Wp1, bp1, st + 2624);

  qkv_k<<<dim3(128, 4), 256, 0, stream>>>(
      t1, st + 512, g1, b1, Wq, bq, Wk, bk, Wv, bv, xq, xk, xv);

  wstats_k<<<1024, 256, 0, stream>>>(xk, xq, p, idx, Wp1, bp1, gp, bpp,
                                     st + 2624, Wp2, bp2, pws);
  red_k<1024, 4><<<32, 256, 0, stream>>>(pws, st + 1024, 512);

  w1gemm_k<<<2048, 256, 0, stream>>>(xk, xq, p, idx, Wp1, bp1, gp, bpp,
                                     st + 2624, Wp2, bp2, st + 1024,
                                     gw1, bw1, Ww1t, bww1, w1, pw1);
  red_k<2048, 16><<<16, 256, 0, stream>>>(pw1, st + 2560, 64);

  aggr_k<<<8192, 256, 0, stream>>>(w1, st + 2560, gw2, bw2, Ww2, bww2, xv,
                                   p, idx, Wp1, bp1, gp, bpp, st + 2624,
                                   Wp2, bp2, y);
  stats256_k<<<256, 256, 0, stream>>>(y, psy);
  red_k<256, 2><<<16, 256, 0, stream>>>(psy, st + 1536, 512);

  mfgemm_k<u16, u16, true, true><<<dim3(128, 4), 256, 20480, stream>>>(
      y, st + 1536, g2, b2, INV_N, W3, t3, st + 2048, 256, 256);

  final_k<<<8192, 256, 0, stream>>>(t0, st + 0, g_pa, b_pa,
                                    t3, st + 2048, g3, b3, (float*)d_out);
}

// Round 26
// 185.193 us; speedup vs baseline: 1.0511x; 1.0511x over previous
//
#include <hip/hip_runtime.h>
#include <hip/hip_bf16.h>

// N=8192, K=16, CIN=64, C=256, S=8, C/S=32 ; float tensors are float32.
#define INV_N  (1.0f/8192.0f)
#define INV_NK (1.0f/131072.0f)

typedef __attribute__((ext_vector_type(8))) short bf16x8;
typedef __attribute__((ext_vector_type(4))) float f32x4;
typedef unsigned short u16;

__device__ __forceinline__ u16 f2b(float f) {   // f32 -> bf16 RNE
  unsigned u = __float_as_uint(f);
  return (u16)((u + 0x7FFFu + ((u >> 16) & 1u)) >> 16);
}
__device__ __forceinline__ float b2f(u16 u) {
  return __uint_as_float(((unsigned)u) << 16);
}

__device__ __forceinline__ float bn_ap(float v, const float* st, int C, int ch,
                                       float inv, float g, float b) {
  float m = st[ch] * inv;
  float var = st[C + ch] * inv - m * m;
  return (v - m) * rsqrtf(var + 1e-5f) * g + b;
}

// ---------------------------------------------------------------- prep
__launch_bounds__(256)
__global__ void prep_k(const float* __restrict__ p, const int* __restrict__ o,
                       const float* __restrict__ Ww1,
                       float4* __restrict__ pp, u16* __restrict__ Ww1t,
                       float* __restrict__ st, float* __restrict__ out) {
  int b = blockIdx.x, t = threadIdx.x;
  int e = b*256 + t;
  if (b < 16) st[b*256 + t] = 0.f;
  if (e < 24576) out[e] = p[e];
  if (e == 0) out[24576 + 2097152] = (float)o[0];
  if (e < 8192) {
    float x = p[e*3+0], y = p[e*3+1], z = p[e*3+2];
    pp[e] = make_float4(x, y, z, (x*x + y*y) + z*z);
  }
  if (b >= 88) {
    int q = (b - 88)*1024 + t*4;
#pragma unroll
    for (int ii = 0; ii < 4; ++ii) {
      int e2 = q + ii;
      int k = e2 >> 5, n = e2 & 31;
      Ww1t[n*256 + k] = f2b(Ww1[e2]);
    }
  }
}

// ---------------------------------------------------------------- generic partial-sum reduce
template<int ROWS, int SPLIT>
__launch_bounds__(256)
__global__ void red_k(const float* __restrict__ part, float* __restrict__ outp,
                      int width) {
  int ncg = width >> 6;
  int cg = blockIdx.x % ncg, sp = blockIdx.x / ncg;
  int lane = threadIdx.x & 63, chunk = threadIdx.x >> 6;
  int c = cg*64 + lane;
  constexpr int R  = ROWS / SPLIT;
  constexpr int RC = R / 4;
  float s = 0.f;
  int i0 = sp*R + chunk*RC;
#pragma unroll 4
  for (int i = i0; i < i0 + RC; ++i) s += part[(size_t)i*width + c];
  __shared__ float red[4][64];
  red[chunk][lane] = s;
  __syncthreads();
  if (threadIdx.x < 64) {
    float v = red[0][lane] + red[1][lane] + red[2][lane] + red[3][lane];
    if (SPLIT == 1) outp[c] = v;
    else atomicAdd(&outp[c], v);
  }
}

// ---------------------------------------------------------------- KNN v8: 1 query/wave, med3 insert chain
__device__ __forceinline__ void knn_dev(char* smem, const float4* __restrict__ pp,
                                        int* __restrict__ idxo, int kb) {
  float4* buf = (float4*)smem;                 // 1024 float4 = 16 KB
  int t = threadIdx.x;
  int wave = t >> 6, lane = t & 63;
  int q = kb*4 + wave;
  float4 qv = pp[q];
  const float BIG = __uint_as_float(0x7F7FFFFFu);
  float d[3];
#pragma unroll
  for (int s = 0; s < 3; ++s) d[s] = BIG;
  for (int ch = 0; ch < 8; ++ch) {
#pragma unroll
    for (int s = 0; s < 4; ++s)
      buf[s*256 + t] = pp[ch*1024 + s*256 + t];
    __syncthreads();
#pragma unroll 4
    for (int it = 0; it < 16; ++it) {
      int jl = it*64 + lane;
      float4 c = buf[jl];
      int j = ch*1024 + jl;
      float dot = qv.x*c.x + (qv.y*c.y + qv.z*c.z);
      float d2 = __fmaf_rn(-2.0f, dot, qv.w + c.w);
      float pk = __uint_as_float((__float_as_uint(d2) & 0xFFFFE000u) | (unsigned)j);
      // sorted insert with single-instruction med3 (identical math to
      // fminf(fmaxf(lo,pk),hi) under the d0<=d1<=d2 invariant)
      d[2] = __builtin_amdgcn_fmed3f(pk, d[1], d[2]);
      d[1] = __builtin_amdgcn_fmed3f(pk, d[0], d[1]);
      d[0] = fminf(d[0], pk);
    }
    __syncthreads();
  }
  for (int r = 0; r < 16; ++r) {
    float bd = d[0];
#pragma unroll
    for (int m = 1; m < 64; m <<= 1)
      bd = fminf(bd, __shfl_xor(bd, m));
    if (lane == 0) idxo[q*16 + r] = (int)(__float_as_uint(bd) & 0x1FFFu);
    if (d[0] == bd) { d[0] = d[1]; d[1] = d[2]; d[2] = BIG; }
  }
}

// ---------------------------------------------------------------- MFMA GEMM device body (20480 B smem)
template<typename TA, typename TO, bool BNA, bool STATS>
__device__ __forceinline__ void mfgemm_dev(char* smem,
    const TA* __restrict__ A, const float* __restrict__ st,
    const float* __restrict__ g, const float* __restrict__ bb, float inv_cnt,
    const float* __restrict__ W, TO* __restrict__ out,
    float* __restrict__ stout, int KA, int NOUT, int bm, int bn_) {
  short (*As)[72] = (short(*)[72])smem;
  short (*Bt)[72] = (short(*)[72])(smem + 9216);
  float* lscl = (float*)(smem + 18432);
  float* lsft = (float*)(smem + 19456);
  int t = threadIdx.x;
  int m0 = bm * 64, n0 = bn_ * 64;
  if (BNA) {
    for (int e = t; e < KA; e += 256) {
      float m = st[e] * inv_cnt;
      float var = st[KA + e] * inv_cnt - m*m;
      float sc = rsqrtf(var + 1e-5f) * g[e];
      lscl[e] = sc; lsft[e] = bb[e] - m*sc;
    }
    __syncthreads();
  }
  const f32x4 zero = {0.f, 0.f, 0.f, 0.f};
  f32x4 acc[2][2] = {{zero, zero}, {zero, zero}};
  int wv = t >> 6, l = t & 63;
  int wm = wv & 1, wn = wv >> 1;
  int lr = l & 15, lk = (l >> 4) * 8;
  int ra = t >> 4, qa = t & 15;
  int bn = t & 63, bkc = t >> 6;
  for (int k0 = 0; k0 < KA; k0 += 64) {
#pragma unroll
    for (int rp = 0; rp < 4; ++rp) {
      int r = rp*16 + ra;
      float vv[4];
      if constexpr (sizeof(TA) == 4) {
        float4 av = *(const float4*)((const float*)A + (size_t)(m0 + r)*KA + k0 + qa*4);
        vv[0] = av.x; vv[1] = av.y; vv[2] = av.z; vv[3] = av.w;
      } else {
        short4 av = *(const short4*)((const u16*)A + (size_t)(m0 + r)*KA + k0 + qa*4);
#pragma unroll
        for (int jj = 0; jj < 4; ++jj) vv[jj] = b2f(((u16*)&av)[jj]);
      }
      short4 s;
#pragma unroll
      for (int jj = 0; jj < 4; ++jj) {
        float v = vv[jj];
        if (BNA) { int ch = k0 + qa*4 + jj; v = fmaxf(fmaf(v, lscl[ch], lsft[ch]), 0.f); }
        ((u16*)&s)[jj] = f2b(v);
      }
      *(short4*)&As[r][qa*4] = s;
    }
    {
      float v[16];
#pragma unroll
      for (int j2 = 0; j2 < 16; ++j2)
        v[j2] = W[(size_t)(k0 + bkc*16 + j2)*NOUT + n0 + bn];
      bf16x8 w0, w1v;
#pragma unroll
      for (int j2 = 0; j2 < 8; ++j2) {
        w0[j2]  = (short)f2b(v[j2]);
        w1v[j2] = (short)f2b(v[8 + j2]);
      }
      *(bf16x8*)&Bt[bn][bkc*16]     = w0;
      *(bf16x8*)&Bt[bn][bkc*16 + 8] = w1v;
    }
    __syncthreads();
#pragma unroll
    for (int fk = 0; fk < 2; ++fk) {
      bf16x8 a0 = *(const bf16x8*)&As[wm*32 +      lr][fk*32 + lk];
      bf16x8 a1 = *(const bf16x8*)&As[wm*32 + 16 + lr][fk*32 + lk];
      bf16x8 b0 = *(const bf16x8*)&Bt[wn*32 +      lr][fk*32 + lk];
      bf16x8 b1 = *(const bf16x8*)&Bt[wn*32 + 16 + lr][fk*32 + lk];
      acc[0][0] = __builtin_amdgcn_mfma_f32_16x16x32_bf16(a0, b0, acc[0][0], 0, 0, 0);
      acc[0][1] = __builtin_amdgcn_mfma_f32_16x16x32_bf16(a0, b1, acc[0][1], 0, 0, 0);
      acc[1][0] = __builtin_amdgcn_mfma_f32_16x16x32_bf16(a1, b0, acc[1][0], 0, 0, 0);
      acc[1][1] = __builtin_amdgcn_mfma_f32_16x16x32_bf16(a1, b1, acc[1][1], 0, 0, 0);
    }
    __syncthreads();
  }
#pragma unroll
  for (int fn = 0; fn < 2; ++fn) {
    int col = n0 + wn*32 + fn*16 + lr;
    float s1 = 0.f, s2 = 0.f;
#pragma unroll
    for (int fm = 0; fm < 2; ++fm) {
#pragma unroll
      for (int r = 0; r < 4; ++r) {
        int row = m0 + wm*32 + fm*16 + (l >> 4)*4 + r;
        float v = acc[fm][fn][r];
        if constexpr (sizeof(TO) == 4) out[(size_t)row*NOUT + col] = v;
        else                           out[(size_t)row*NOUT + col] = f2b(v);
        if (STATS) { s1 += v; s2 += v*v; }
      }
    }
    if (STATS) {
      s1 += __shfl_xor(s1, 16); s1 += __shfl_xor(s1, 32);
      s2 += __shfl_xor(s2, 16); s2 += __shfl_xor(s2, 32);
      if (l < 16) {
        atomicAdd(&stout[col], s1);
        atomicAdd(&stout[NOUT + col], s2);
      }
    }
  }
}

// ---------------------------------------------------------------- p_r helpers
__device__ __forceinline__ void comp_pr1(const float* p, int i, int j,
                                         const float* Wp1, const float* bp1,
                                         float pr1[3]) {
  float rx = p[j*3+0] - p[i*3+0];
  float ry = p[j*3+1] - p[i*3+1];
  float rz = p[j*3+2] - p[i*3+2];
#pragma unroll
  for (int c = 0; c < 3; ++c)
    pr1[c] = rx*Wp1[c] + ry*Wp1[3+c] + rz*Wp1[6+c] + bp1[c];
}

__device__ __forceinline__ void comp_prv(const float* p, int i, int j,
                                         const float* Wp1, const float* bp1,
                                         const float* gp, const float* bpp,
                                         const float* sp, float o3[3]) {
  float pr1[3];
  comp_pr1(p, i, j, Wp1, bp1, pr1);
#pragma unroll
  for (int c = 0; c < 3; ++c)
    o3[c] = fmaxf(bn_ap(pr1[c], sp, 3, c, INV_NK, gp[c], bpp[c]), 0.0f);
}

// ---------------------------------------------------------------- prstats device body
__device__ __forceinline__ void prstats_dev(char* smem,
    const float* __restrict__ p, const int* __restrict__ idx,
    const float* Wp1, const float* bp1, float* __restrict__ sp, int pb) {
  float s[3] = {0,0,0}, s2[3] = {0,0,0};
  for (int it = 0; it < 4; ++it) {
    int e = pb*1024 + it*256 + threadIdx.x;
    int i = e >> 4;
    int j = idx[e] & 8191;
    float pr1[3];
    comp_pr1(p, i, j, Wp1, bp1, pr1);
#pragma unroll
    for (int c = 0; c < 3; ++c) { s[c] += pr1[c]; s2[c] += pr1[c]*pr1[c]; }
  }
#pragma unroll
  for (int m = 1; m < 64; m <<= 1) {
#pragma unroll
    for (int c = 0; c < 3; ++c) {
      s[c]  += __shfl_xor(s[c],  m);
      s2[c] += __shfl_xor(s2[c], m);
    }
  }
  float (*red)[6] = (float(*)[6])smem;
  int wv = threadIdx.x >> 6, lane = threadIdx.x & 63;
  if (lane == 0) {
#pragma unroll
    for (int c = 0; c < 3; ++c) { red[wv][c] = s[c]; red[wv][3+c] = s2[c]; }
  }
  __syncthreads();
  if (threadIdx.x < 6) {
    float v = red[0][threadIdx.x] + red[1][threadIdx.x] +
              red[2][threadIdx.x] + red[3][threadIdx.x];
    atomicAdd(&sp[threadIdx.x], v);
  }
}

// ---------------------------------------------------------------- packed: mfgemm1 (512) || knn-full (2048)
__launch_bounds__(256)
__global__ void gemmknn_k(const float* __restrict__ x, const float* __restrict__ W_pa,
                          u16* __restrict__ t0, float* __restrict__ st0,
                          const float4* __restrict__ pp, int* __restrict__ idxo) {
  extern __shared__ char smem[];
  int b = blockIdx.x;
  if (b < 512)
    mfgemm_dev<float, u16, false, true>(smem, x, nullptr, nullptr, nullptr, 0.f,
                                        W_pa, t0, st0, 64, 256, b & 127, b >> 7);
  else
    knn_dev(smem, pp, idxo, b - 512);        // kb 0..2047 -> all 8192 queries
}

// ---------------------------------------------------------------- packed: mfgemm2 (512) || prstats (128)
__launch_bounds__(256)
__global__ void gemmpr_k(const u16* __restrict__ t0, const float* __restrict__ st0,
                         const float* __restrict__ g_pa, const float* __restrict__ b_pa,
                         const float* __restrict__ W1, u16* __restrict__ t1,
                         float* __restrict__ st1,
                         const float* __restrict__ p, const int* __restrict__ idx,
                         const float* __restrict__ Wp1, const float* __restrict__ bp1,
                         float* __restrict__ sp) {
  extern __shared__ char smem[];
  int b = blockIdx.x;
  if (b < 512)
    mfgemm_dev<u16, u16, true, true>(smem, t0, st0, g_pa, b_pa, INV_N,
                                     W1, t1, st1, 256, 256, b & 127, b >> 7);
  else
    prstats_dev(smem, p, idx, Wp1, bp1, sp, b - 512);
}

// ---------------------------------------------------------------- standalone mfgemm wrapper (W3 pass)
template<typename TA, typename TO, bool BNA, bool STATS>
__launch_bounds__(256)
__global__ void mfgemm_k(const TA* __restrict__ A, const float* __restrict__ st,
                         const float* __restrict__ g, const float* __restrict__ bb,
                         float inv_cnt,
                         const float* __restrict__ W, TO* __restrict__ out,
                         float* __restrict__ stout, int KA, int NOUT) {
  extern __shared__ char smem[];
  mfgemm_dev<TA, TO, BNA, STATS>(smem, A, st, g, bb, inv_cnt, W, out, stout,
                                 KA, NOUT, blockIdx.x, blockIdx.y);
}

// ---------------------------------------------------------------- fused Q/K/V MFMA (bf16 in/out, static smem)
__launch_bounds__(256)
__global__ void qkv_k(const u16* __restrict__ t1, const float* __restrict__ st,
                      const float* __restrict__ g1, const float* __restrict__ b1,
                      const float* __restrict__ Wq, const float* __restrict__ bq,
                      const float* __restrict__ Wk, const float* __restrict__ bk,
                      const float* __restrict__ Wv, const float* __restrict__ bv,
                      u16* __restrict__ xq, u16* __restrict__ xk, u16* __restrict__ xv) {
  __shared__ short As[64][72];
  __shared__ short Bt[3][64][72];
  __shared__ float lscl[256], lsft[256];
  int t = threadIdx.x;
  int m0 = blockIdx.x * 64, n0 = blockIdx.y * 64;
  {
    int e = t;
    float m = st[e] * INV_N;
    float var = st[256 + e] * INV_N - m*m;
    float sc = rsqrtf(var + 1e-5f) * g1[e];
    lscl[e] = sc; lsft[e] = b1[e] - m*sc;
  }
  __syncthreads();
  const f32x4 zero = {0.f, 0.f, 0.f, 0.f};
  f32x4 acc[3][2][2];
#pragma unroll
  for (int w = 0; w < 3; ++w)
#pragma unroll
    for (int i = 0; i < 2; ++i)
#pragma unroll
      for (int j = 0; j < 2; ++j) acc[w][i][j] = zero;
  int wv = t >> 6, l = t & 63;
  int wm = wv & 1, wn = wv >> 1;
  int lr = l & 15, lk = (l >> 4) * 8;
  int ra = t >> 4, qa = t & 15;
  int bn = t & 63, bkc = t >> 6;
  const float* Ws[3] = {Wq, Wk, Wv};
  for (int k0 = 0; k0 < 256; k0 += 64) {
#pragma unroll
    for (int rp = 0; rp < 4; ++rp) {
      int r = rp*16 + ra;
      short4 av = *(const short4*)(t1 + (size_t)(m0 + r)*256 + k0 + qa*4);
      short4 s;
#pragma unroll
      for (int jj = 0; jj < 4; ++jj) {
        int ch = k0 + qa*4 + jj;
        float v = fmaxf(fmaf(b2f(((u16*)&av)[jj]), lscl[ch], lsft[ch]), 0.f);
        ((u16*)&s)[jj] = f2b(v);
      }
      *(short4*)&As[r][qa*4] = s;
    }
#pragma unroll
    for (int w = 0; w < 3; ++w) {
      float v[16];
#pragma unroll
      for (int j2 = 0; j2 < 16; ++j2)
        v[j2] = Ws[w][(size_t)(k0 + bkc*16 + j2)*256 + n0 + bn];
      bf16x8 w0, w1v;
#pragma unroll
      for (int j2 = 0; j2 < 8; ++j2) {
        w0[j2]  = (short)f2b(v[j2]);
        w1v[j2] = (short)f2b(v[8 + j2]);
      }
      *(bf16x8*)&Bt[w][bn][bkc*16]     = w0;
      *(bf16x8*)&Bt[w][bn][bkc*16 + 8] = w1v;
    }
    __syncthreads();
#pragma unroll
    for (int fk = 0; fk < 2; ++fk) {
      bf16x8 a0 = *(const bf16x8*)&As[wm*32 +      lr][fk*32 + lk];
      bf16x8 a1 = *(const bf16x8*)&As[wm*32 + 16 + lr][fk*32 + lk];
#pragma unroll
      for (int w = 0; w < 3; ++w) {
        bf16x8 b0 = *(const bf16x8*)&Bt[w][wn*32 +      lr][fk*32 + lk];
        bf16x8 b1 = *(const bf16x8*)&Bt[w][wn*32 + 16 + lr][fk*32 + lk];
        acc[w][0][0] = __builtin_amdgcn_mfma_f32_16x16x32_bf16(a0, b0, acc[w][0][0], 0, 0, 0);
        acc[w][0][1] = __builtin_amdgcn_mfma_f32_16x16x32_bf16(a0, b1, acc[w][0][1], 0, 0, 0);
        acc[w][1][0] = __builtin_amdgcn_mfma_f32_16x16x32_bf16(a1, b0, acc[w][1][0], 0, 0, 0);
        acc[w][1][1] = __builtin_amdgcn_mfma_f32_16x16x32_bf16(a1, b1, acc[w][1][1], 0, 0, 0);
      }
    }
    __syncthreads();
  }
  u16* outs[3] = {xq, xk, xv};
  const float* bs[3] = {bq, bk, bv};
#pragma unroll
  for (int w = 0; w < 3; ++w) {
#pragma unroll
    for (int fn = 0; fn < 2; ++fn) {
      int col = n0 + wn*32 + fn*16 + lr;
      float bvv = bs[w][col];
#pragma unroll
      for (int fm = 0; fm < 2; ++fm) {
#pragma unroll
        for (int r = 0; r < 4; ++r) {
          int row = m0 + wm*32 + fm*16 + (l >> 4)*4 + r;
          outs[w][(size_t)row*256 + col] = f2b(acc[w][fm][fn][r] + bvv);
        }
      }
    }
  }
}

// ---------------------------------------------------------------- y stats -> partials (bf16 in)
__launch_bounds__(256)
__global__ void stats256_k(const u16* __restrict__ X, float* __restrict__ psy) {
  int c = threadIdx.x;
  int r0 = blockIdx.x * 32;
  float s1 = 0.f, s2 = 0.f;
  for (int r = 0; r < 32; ++r) {
    float v = b2f(X[(size_t)(r0 + r)*256 + c]);
    s1 += v; s2 += v*v;
  }
  psy[(size_t)blockIdx.x*512 + c]       = s1;
  psy[(size_t)blockIdx.x*512 + 256 + c] = s2;
}

// ---------------------------------------------------------------- stats of w -> partials
__launch_bounds__(256)
__global__ void wstats_k(const u16* __restrict__ xk, const u16* __restrict__ xq,
                         const float* __restrict__ p, const int* __restrict__ idx,
                         const float* Wp1, const float* bp1, const float* gp, const float* bpp,
                         const float* sp, const float* __restrict__ Wp2, const float* bp2,
                         float* __restrict__ pws) {
  __shared__ float prv[8][16][4];
  __shared__ int   jidx[8][16];
  int base = blockIdx.x * 8;
  int t = threadIdx.x;
  if (t < 128) {
    int pt = t >> 4, k = t & 15;
    int j = idx[(base + pt)*16 + k] & 8191;
    jidx[pt][k] = j;
    float o3[3];
    comp_prv(p, base + pt, j, Wp1, bp1, gp, bpp, sp, o3);
    prv[pt][k][0] = o3[0]; prv[pt][k][1] = o3[1]; prv[pt][k][2] = o3[2];
  }
  __syncthreads();
  int c = t;
  float wp0 = Wp2[c], wp1v = Wp2[256+c], wp2v = Wp2[512+c];
  float bbv = bp2[c];
  float s1 = 0.f, s2 = 0.f;
  for (int pt = 0; pt < 8; ++pt) {
    int i = base + pt;
    float xqv = b2f(xq[(size_t)i*256 + c]);
    u16 kvals[16];
#pragma unroll
    for (int k = 0; k < 16; ++k)
      kvals[k] = xk[(size_t)jidx[pt][k]*256 + c];
#pragma unroll
    for (int k = 0; k < 16; ++k) {
      float pr = prv[pt][k][0]*wp0 + prv[pt][k][1]*wp1v + prv[pt][k][2]*wp2v + bbv;
      float wval = b2f(kvals[k]) - xqv + pr;
      s1 += wval; s2 += wval*wval;
    }
  }
  pws[(size_t)blockIdx.x*512 + c]       = s1;
  pws[(size_t)blockIdx.x*512 + 256 + c] = s2;
}

// ---------------------------------------------------------------- w1gemm: gather + partial-store stats
__launch_bounds__(256)
__global__ void w1gemm_k(const u16* __restrict__ xk, const u16* __restrict__ xq,
                         const float* __restrict__ p, const int* __restrict__ idx,
                         const float* Wp1, const float* bp1, const float* gp, const float* bpp,
                         const float* sp, const float* __restrict__ Wp2, const float* bp2,
                         const float* sw, const float* gw1, const float* bw1,
                         const u16* __restrict__ Ww1t, const float* bww1,
                         u16* __restrict__ w1, float* __restrict__ pw1) {
  __shared__ short sA[64][264];
  __shared__ float prv[64][3];
  __shared__ int   jrow[64];
  __shared__ float sred[256];
  int t = threadIdx.x;
  int base4 = blockIdx.x * 4;
  if (t < 64) {
    int grow = blockIdx.x*64 + t;
    int j = idx[grow] & 8191;
    jrow[t] = j;
    float o3[3];
    comp_prv(p, grow >> 4, j, Wp1, bp1, gp, bpp, sp, o3);
    prv[t][0] = o3[0]; prv[t][1] = o3[1]; prv[t][2] = o3[2];
  }
  __syncthreads();
  {
    int o = t & 31, rs = t >> 5;
    int ch0 = o*8;
    int jr[8];
#pragma unroll
    for (int ii = 0; ii < 8; ++ii) jr[ii] = jrow[ii*8 + rs];
    bf16x8 kvv[8], qvv[8];
#pragma unroll
    for (int ii = 0; ii < 8; ++ii) {
      int r = ii*8 + rs;
      kvv[ii] = *(const bf16x8*)(xk + (size_t)jr[ii]*256 + ch0);
      qvv[ii] = *(const bf16x8*)(xq + (size_t)(base4 + (r >> 4))*256 + ch0);
    }
    float sclv[8], sftv[8], w0v[8], w1vv[8], w2v[8], b2v[8];
#pragma unroll
    for (int h = 0; h < 2; ++h) {
      float4 swm = *(const float4*)(sw + ch0 + h*4);
      float4 sws = *(const float4*)(sw + 256 + ch0 + h*4);
      float4 g4  = *(const float4*)(gw1 + ch0 + h*4);
      float4 bb4 = *(const float4*)(bw1 + ch0 + h*4);
      float4 p0v = *(const float4*)(Wp2 + ch0 + h*4);
      float4 p1v = *(const float4*)(Wp2 + 256 + ch0 + h*4);
      float4 p2v = *(const float4*)(Wp2 + 512 + ch0 + h*4);
      float4 bp4 = *(const float4*)(bp2 + ch0 + h*4);
      float mv[4] = {swm.x, swm.y, swm.z, swm.w};
      float sv[4] = {sws.x, sws.y, sws.z, sws.w};
      float gv[4] = {g4.x, g4.y, g4.z, g4.w};
      float bv[4] = {bb4.x, bb4.y, bb4.z, bb4.w};
      float a0[4] = {p0v.x, p0v.y, p0v.z, p0v.w};
      float a1[4] = {p1v.x, p1v.y, p1v.z, p1v.w};
      float a2[4] = {p2v.x, p2v.y, p2v.z, p2v.w};
      float a3[4] = {bp4.x, bp4.y, bp4.z, bp4.w};
#pragma unroll
      for (int jj = 0; jj < 4; ++jj) {
        int e = h*4 + jj;
        float m = mv[jj]*INV_NK;
        float var = sv[jj]*INV_NK - m*m;
        float sc = rsqrtf(var + 1e-5f)*gv[jj];
        sclv[e] = sc; sftv[e] = bv[jj] - m*sc;
        w0v[e] = a0[jj]; w1vv[e] = a1[jj]; w2v[e] = a2[jj]; b2v[e] = a3[jj];
      }
    }
#pragma unroll
    for (int ii = 0; ii < 8; ++ii) {
      int r = ii*8 + rs;
      float p0 = prv[r][0], p1 = prv[r][1], p2 = prv[r][2];
      bf16x8 av;
#pragma unroll
      for (int e = 0; e < 8; ++e) {
        float v = b2f((u16)kvv[ii][e]) - b2f((u16)qvv[ii][e])
                + p0*w0v[e] + p1*w1vv[e] + p2*w2v[e] + b2v[e];
        v = fmaxf(fmaf(v, sclv[e], sftv[e]), 0.f);
        av[e] = (short)f2b(v);
      }
      *(bf16x8*)&sA[r][ch0] = av;
    }
  }
  __syncthreads();
  const f32x4 zero = {0.f,0.f,0.f,0.f};
  f32x4 acc[2] = {zero, zero};
  int wv = t >> 6, l = t & 63;
  int lr = l & 15, hi = l >> 4;
#pragma unroll
  for (int k0 = 0; k0 < 8; ++k0) {
    int kb = k0*32 + hi*8;
    bf16x8 a  = *(const bf16x8*)&sA[wv*16 + lr][kb];
    bf16x8 b0 = *(const bf16x8*)(Ww1t + (size_t)lr*256      + kb);
    bf16x8 b1 = *(const bf16x8*)(Ww1t + (size_t)(16+lr)*256 + kb);
    acc[0] = __builtin_amdgcn_mfma_f32_16x16x32_bf16(a, b0, acc[0], 0, 0, 0);
    acc[1] = __builtin_amdgcn_mfma_f32_16x16x32_bf16(a, b1, acc[1], 0, 0, 0);
  }
#pragma unroll
  for (int fn = 0; fn < 2; ++fn) {
    int col = fn*16 + lr;
    float bv = bww1[col];
    float s1 = 0.f, s2 = 0.f;
#pragma unroll
    for (int r = 0; r < 4; ++r) {
      int grow = blockIdx.x*64 + wv*16 + hi*4 + r;
      float v = acc[fn][r] + bv;
      w1[(size_t)grow*32 + col] = f2b(v);
      s1 += v; s2 += v*v;
    }
    s1 += __shfl_xor(s1, 16); s1 += __shfl_xor(s1, 32);
    s2 += __shfl_xor(s2, 16); s2 += __shfl_xor(s2, 32);
    if (l < 16) { sred[(wv*2+fn)*16 + lr] = s1; sred[128 + (wv*2+fn)*16 + lr] = s2; }
  }
  __syncthreads();
  if (t < 32) {
    float a = 0.f, b = 0.f;
#pragma unroll
    for (int w2 = 0; w2 < 4; ++w2) {
      a += sred[(w2*2 + (t >> 4))*16 + (t & 15)];
      b += sred[128 + (w2*2 + (t >> 4))*16 + (t & 15)];
    }
    pw1[(size_t)blockIdx.x*64 + t]      = a;
    pw1[(size_t)blockIdx.x*64 + 32 + t] = b;
  }
}

// ---------------------------------------------------------------- aggr (1 query/block, proven)
__launch_bounds__(256)
__global__ void aggr_k(const u16* __restrict__ w1, const float* sw1,
                       const float* gw2, const float* bw2,
                       const float* __restrict__ Ww2, const float* bww2,
                       const u16* __restrict__ xv,
                       const float* __restrict__ p, const int* __restrict__ idx,
                       const float* Wp1, const float* bp1, const float* gp, const float* bpp,
                       const float* sp, const float* __restrict__ Wp2, const float* bp2,
                       u16* __restrict__ y) {
  __shared__ float lw1[16][32];
  __shared__ float lW2[32][32];
  __shared__ float sw2[16][33];
  __shared__ float prv[16][4];
  __shared__ int   jidx[16];
  int i = blockIdx.x, t = threadIdx.x;
  for (int e = t; e < 1024; e += 256) lW2[e >> 5][e & 31] = Ww2[e];
  for (int e = t; e < 512; e += 256) {
    int c32 = e & 31;
    float v = b2f(w1[(size_t)i*512 + e]);
    v = fmaxf(bn_ap(v, sw1, 32, c32, INV_NK, gw2[c32], bw2[c32]), 0.0f);
    lw1[e >> 5][c32] = v;
  }
  if (t < 16) jidx[t] = idx[i*16 + t] & 8191;
  __syncthreads();
  if (t < 16) {
    float o3[3];
    comp_prv(p, i, jidx[t], Wp1, bp1, gp, bpp, sp, o3);
    prv[t][0] = o3[0]; prv[t][1] = o3[1]; prv[t][2] = o3[2];
  }
  for (int e = t; e < 512; e += 256) {
    int k = e >> 5, c32 = e & 31;
    float a = bww2[c32];
#pragma unroll
    for (int j = 0; j < 32; ++j) a += lw1[k][j] * lW2[j][c32];
    sw2[k][c32] = a;
  }
  __syncthreads();
  if (t < 32) {
    float mx = -3.0e38f;
#pragma unroll
    for (int k = 0; k < 16; ++k) mx = fmaxf(mx, sw2[k][t]);
    float s = 0.f;
#pragma unroll
    for (int k = 0; k < 16; ++k) { float e2 = expf(sw2[k][t] - mx); sw2[k][t] = e2; s += e2; }
    float r = 1.0f / s;
#pragma unroll
    for (int k = 0; k < 16; ++k) sw2[k][t] *= r;
  }
  __syncthreads();
  int c = t;
  float wp0 = Wp2[c], wp1v = Wp2[256+c], wp2v = Wp2[512+c];
  float bbv = bp2[c];
  int c32 = c & 31;
  float acc = 0.f;
#pragma unroll
  for (int k = 0; k < 16; ++k) {
    int j = jidx[k];
    float pr = prv[k][0]*wp0 + prv[k][1]*wp1v + prv[k][2]*wp2v + bbv;
    float xvv = b2f(xv[(size_t)j*256 + c]);
    acc += (xvv + pr) * sw2[k][c32];
  }
  y[(size_t)i*256 + c] = f2b(acc);
}

// ---------------------------------------------------------------- epilogue (bf16 in)
__launch_bounds__(256)
__global__ void final_k(const u16* __restrict__ t0, const float* s0,
                        const float* g0, const float* b0,
                        const u16* __restrict__ t3, const float* s3,
                        const float* g3, const float* b3,
                        float* __restrict__ out) {
  int i = blockIdx.x, c = threadIdx.x;
  size_t off = (size_t)i*256 + c;
  float h0 = fmaxf(bn_ap(b2f(t0[off]), s0, 256, c, INV_N, g0[c], b0[c]), 0.0f);
  float v3 = bn_ap(b2f(t3[off]), s3, 256, c, INV_N, g3[c], b3[c]);
  out[24576 + off] = fmaxf(v3 + h0, 0.0f);
}

// ---------------------------------------------------------------- launch
extern "C" void kernel_launch(void* const* d_in, const int* in_sizes, int n_in,
                              void* d_out, int out_size, void* d_ws, size_t ws_size,
                              hipStream_t stream) {
  (void)in_sizes; (void)n_in; (void)out_size; (void)ws_size;
  const float* p    = (const float*)d_in[0];
  const float* x    = (const float*)d_in[1];
  const int*   o    = (const int*)  d_in[2];
  const float* W_pa = (const float*)d_in[3];
  const float* g_pa = (const float*)d_in[4];
  const float* b_pa = (const float*)d_in[5];
  const float* W1   = (const float*)d_in[6];
  const float* g1   = (const float*)d_in[7];
  const float* b1   = (const float*)d_in[8];
  const float* Wq   = (const float*)d_in[9];
  const float* bq   = (const float*)d_in[10];
  const float* Wk   = (const float*)d_in[11];
  const float* bk   = (const float*)d_in[12];
  const float* Wv   = (const float*)d_in[13];
  const float* bv   = (const float*)d_in[14];
  const float* Wp1  = (const float*)d_in[15];
  const float* bp1  = (const float*)d_in[16];
  const float* gp   = (const float*)d_in[17];
  const float* bpp  = (const float*)d_in[18];
  const float* Wp2  = (const float*)d_in[19];
  const float* bp2  = (const float*)d_in[20];
  const float* gw1  = (const float*)d_in[21];
  const float* bw1  = (const float*)d_in[22];
  const float* Ww1  = (const float*)d_in[23];
  const float* bww1 = (const float*)d_in[24];
  const float* gw2  = (const float*)d_in[25];
  const float* bw2  = (const float*)d_in[26];
  const float* Ww2  = (const float*)d_in[27];
  const float* bww2 = (const float*)d_in[28];
  const float* g2   = (const float*)d_in[29];
  const float* b2   = (const float*)d_in[30];
  const float* W3   = (const float*)d_in[31];
  const float* g3   = (const float*)d_in[32];
  const float* b3   = (const float*)d_in[33];

  // workspace layout (~34 MB)
  char* ws = (char*)d_ws;
  u16*   t0  = (u16*)  (ws + 0);          // [8192,256] bf16 (live til final_k)
  u16*   t1  = (u16*)  (ws + 4194304);    // [8192,256] bf16 (later: y)
  u16*   xq  = (u16*)  (ws + 8388608);    // [8192,256] bf16 (later: t3)
  u16*   xk  = (u16*)  (ws + 12582912);   // [8192,256] bf16
  u16*   xv  = (u16*)  (ws + 16777216);   // [8192,256] bf16
  u16*   w1  = (u16*)  (ws + 20971520);   // [131072,32] bf16 (8 MB)
  int*   idx = (int*)  (ws + 29360128);   // [8192,16] i32
  float* st  = (float*)(ws + 29884416);   // stats block (16 KB)
  u16*   Ww1t= (u16*)  (ws + 29900800);   // [32][256] bf16 (16 KB)
  float* pw1 = (float*)(ws + 30408704);   // [2048][64] partials (512 KB)
  float* pws = (float*)(ws + 30932992);   // [1024][512] partials (2 MB)
  float* psy = (float*)(ws + 33030144);   // [256][512] partials (512 KB)
  u16*   y   = t1;                        // aggr output (t1 dead after qkv)
  u16*   t3  = xq;                        // aliases xq (dead after w1 stage)
  float4* pp = (float4*)(ws + 20971520);  // aliases w1 (knn finishes first)
  // st offsets: s0=0, s1=512, sw=1024, sy=1536, s3=2048, sw1=2560, sp=2624

  prep_k<<<96, 256, 0, stream>>>(p, o, Ww1, pp, Ww1t, st, (float*)d_out);

  gemmknn_k<<<2560, 256, 20480, stream>>>(x, W_pa, t0, st + 0, pp, idx);

  gemmpr_k<<<640, 256, 20480, stream>>>(t0, st + 0, g_pa, b_pa, W1, t1, st + 512,
                                        p, idx, Wp1, bp1, st + 2624);

  qkv_k<<<dim3(128, 4), 256, 0, stream>>>(
      t1, st + 512, g1, b1, Wq, bq, Wk, bk, Wv, bv, xq, xk, xv);

  wstats_k<<<1024, 256, 0, stream>>>(xk, xq, p, idx, Wp1, bp1, gp, bpp,
                                     st + 2624, Wp2, bp2, pws);
  red_k<1024, 4><<<32, 256, 0, stream>>>(pws, st + 1024, 512);

  w1gemm_k<<<2048, 256, 0, stream>>>(xk, xq, p, idx, Wp1, bp1, gp, bpp,
                                     st + 2624, Wp2, bp2, st + 1024,
                                     gw1, bw1, Ww1t, bww1, w1, pw1);
  red_k<2048, 16><<<16, 256, 0, stream>>>(pw1, st + 2560, 64);

  aggr_k<<<8192, 256, 0, stream>>>(w1, st + 2560, gw2, bw2, Ww2, bww2, xv,
                                   p, idx, Wp1, bp1, gp, bpp, st + 2624,
                                   Wp2, bp2, y);
  stats256_k<<<256, 256, 0, stream>>>(y, psy);
  red_k<256, 2><<<16, 256, 0, stream>>>(psy, st + 1536, 512);

  mfgemm_k<u16, u16, true, true><<<dim3(128, 4), 256, 20480, stream>>>(
      y, st + 1536, g2, b2, INV_N, W3, t3, st + 2048, 256, 256);

  final_k<<<8192, 256, 0, stream>>>(t0, st + 0, g_pa, b_pa,
                                    t3, st + 2048, g3, b3, (float*)d_out);
}

// Round 27
// 183.206 us; speedup vs baseline: 1.0625x; 1.0108x over previous
//
#include <hip/hip_runtime.h>
#include <hip/hip_bf16.h>

// N=8192, K=16, CIN=64, C=256, S=8, C/S=32 ; float tensors are float32.
#define INV_N  (1.0f/8192.0f)
#define INV_NK (1.0f/131072.0f)

typedef __attribute__((ext_vector_type(8))) short bf16x8;
typedef __attribute__((ext_vector_type(4))) float f32x4;
typedef unsigned short u16;

__device__ __forceinline__ u16 f2b(float f) {   // f32 -> bf16 RNE
  unsigned u = __float_as_uint(f);
  return (u16)((u + 0x7FFFu + ((u >> 16) & 1u)) >> 16);
}
__device__ __forceinline__ float b2f(u16 u) {
  return __uint_as_float(((unsigned)u) << 16);
}

__device__ __forceinline__ float bn_ap(float v, const float* st, int C, int ch,
                                       float inv, float g, float b) {
  float m = st[ch] * inv;
  float var = st[C + ch] * inv - m * m;
  return (v - m) * rsqrtf(var + 1e-5f) * g + b;
}

// ---------------------------------------------------------------- prep
__launch_bounds__(256)
__global__ void prep_k(const float* __restrict__ p, const int* __restrict__ o,
                       const float* __restrict__ Ww1,
                       float4* __restrict__ pp, u16* __restrict__ Ww1t,
                       float* __restrict__ st, float* __restrict__ out) {
  int b = blockIdx.x, t = threadIdx.x;
  int e = b*256 + t;
  if (b < 16) st[b*256 + t] = 0.f;
  if (e < 24576) out[e] = p[e];
  if (e == 0) out[24576 + 2097152] = (float)o[0];
  if (e < 8192) {
    float x = p[e*3+0], y = p[e*3+1], z = p[e*3+2];
    pp[e] = make_float4(x, y, z, (x*x + y*y) + z*z);
  }
  if (b >= 88) {
    int q = (b - 88)*1024 + t*4;
#pragma unroll
    for (int ii = 0; ii < 4; ++ii) {
      int e2 = q + ii;
      int k = e2 >> 5, n = e2 & 31;
      Ww1t[n*256 + k] = f2b(Ww1[e2]);
    }
  }
}

// ---------------------------------------------------------------- generic partial-sum reduce
template<int ROWS, int SPLIT>
__launch_bounds__(256)
__global__ void red_k(const float* __restrict__ part, float* __restrict__ outp,
                      int width) {
  int ncg = width >> 6;
  int cg = blockIdx.x % ncg, sp = blockIdx.x / ncg;
  int lane = threadIdx.x & 63, chunk = threadIdx.x >> 6;
  int c = cg*64 + lane;
  constexpr int R  = ROWS / SPLIT;
  constexpr int RC = R / 4;
  float s = 0.f;
  int i0 = sp*R + chunk*RC;
#pragma unroll 4
  for (int i = i0; i < i0 + RC; ++i) s += part[(size_t)i*width + c];
  __shared__ float red[4][64];
  red[chunk][lane] = s;
  __syncthreads();
  if (threadIdx.x < 64) {
    float v = red[0][lane] + red[1][lane] + red[2][lane] + red[3][lane];
    if (SPLIT == 1) outp[c] = v;
    else atomicAdd(&outp[c], v);
  }
}

// ---------------------------------------------------------------- KNN v9: 1 query/wave, med3 insert + fma-chain dist
__device__ __forceinline__ void knn_dev(char* smem, const float4* __restrict__ pp,
                                        int* __restrict__ idxo, int kb) {
  float4* buf = (float4*)smem;                 // 1024 float4 = 16 KB
  int t = threadIdx.x;
  int wave = t >> 6, lane = t & 63;
  int q = kb*4 + wave;
  float4 qv = pp[q];
  float m2x = -2.0f*qv.x, m2y = -2.0f*qv.y, m2z = -2.0f*qv.z;
  const float BIG = __uint_as_float(0x7F7FFFFFu);
  float d[3];
#pragma unroll
  for (int s = 0; s < 3; ++s) d[s] = BIG;
  for (int ch = 0; ch < 8; ++ch) {
#pragma unroll
    for (int s = 0; s < 4; ++s)
      buf[s*256 + t] = pp[ch*1024 + s*256 + t];
    __syncthreads();
#pragma unroll 4
    for (int it = 0; it < 16; ++it) {
      int jl = it*64 + lane;
      float4 c = buf[jl];
      int j = ch*1024 + jl;
      // d2 = |q|^2 + |c|^2 - 2 q.c as a pure fma chain (4 VALU ops)
      float d2 = __fmaf_rn(m2x, c.x,
                 __fmaf_rn(m2y, c.y,
                 __fmaf_rn(m2z, c.z, qv.w + c.w)));
      float pk = __uint_as_float((__float_as_uint(d2) & 0xFFFFE000u) | (unsigned)j);
      d[2] = __builtin_amdgcn_fmed3f(pk, d[1], d[2]);
      d[1] = __builtin_amdgcn_fmed3f(pk, d[0], d[1]);
      d[0] = fminf(d[0], pk);
    }
    __syncthreads();
  }
  for (int r = 0; r < 16; ++r) {
    float bd = d[0];
#pragma unroll
    for (int m = 1; m < 64; m <<= 1)
      bd = fminf(bd, __shfl_xor(bd, m));
    if (lane == 0) idxo[q*16 + r] = (int)(__float_as_uint(bd) & 0x1FFFu);
    if (d[0] == bd) { d[0] = d[1]; d[1] = d[2]; d[2] = BIG; }
  }
}

// ---------------------------------------------------------------- MFMA GEMM device body (20480 B smem)
template<typename TA, typename TO, bool BNA, bool STATS>
__device__ __forceinline__ void mfgemm_dev(char* smem,
    const TA* __restrict__ A, const float* __restrict__ st,
    const float* __restrict__ g, const float* __restrict__ bb, float inv_cnt,
    const float* __restrict__ W, TO* __restrict__ out,
    float* __restrict__ stout, int KA, int NOUT, int bm, int bn_) {
  short (*As)[72] = (short(*)[72])smem;
  short (*Bt)[72] = (short(*)[72])(smem + 9216);
  float* lscl = (float*)(smem + 18432);
  float* lsft = (float*)(smem + 19456);
  int t = threadIdx.x;
  int m0 = bm * 64, n0 = bn_ * 64;
  if (BNA) {
    for (int e = t; e < KA; e += 256) {
      float m = st[e] * inv_cnt;
      float var = st[KA + e] * inv_cnt - m*m;
      float sc = rsqrtf(var + 1e-5f) * g[e];
      lscl[e] = sc; lsft[e] = bb[e] - m*sc;
    }
    __syncthreads();
  }
  const f32x4 zero = {0.f, 0.f, 0.f, 0.f};
  f32x4 acc[2][2] = {{zero, zero}, {zero, zero}};
  int wv = t >> 6, l = t & 63;
  int wm = wv & 1, wn = wv >> 1;
  int lr = l & 15, lk = (l >> 4) * 8;
  int ra = t >> 4, qa = t & 15;
  int bn = t & 63, bkc = t >> 6;
  for (int k0 = 0; k0 < KA; k0 += 64) {
#pragma unroll
    for (int rp = 0; rp < 4; ++rp) {
      int r = rp*16 + ra;
      float vv[4];
      if constexpr (sizeof(TA) == 4) {
        float4 av = *(const float4*)((const float*)A + (size_t)(m0 + r)*KA + k0 + qa*4);
        vv[0] = av.x; vv[1] = av.y; vv[2] = av.z; vv[3] = av.w;
      } else {
        short4 av = *(const short4*)((const u16*)A + (size_t)(m0 + r)*KA + k0 + qa*4);
#pragma unroll
        for (int jj = 0; jj < 4; ++jj) vv[jj] = b2f(((u16*)&av)[jj]);
      }
      short4 s;
#pragma unroll
      for (int jj = 0; jj < 4; ++jj) {
        float v = vv[jj];
        if (BNA) { int ch = k0 + qa*4 + jj; v = fmaxf(fmaf(v, lscl[ch], lsft[ch]), 0.f); }
        ((u16*)&s)[jj] = f2b(v);
      }
      *(short4*)&As[r][qa*4] = s;
    }
    {
      float v[16];
#pragma unroll
      for (int j2 = 0; j2 < 16; ++j2)
        v[j2] = W[(size_t)(k0 + bkc*16 + j2)*NOUT + n0 + bn];
      bf16x8 w0, w1v;
#pragma unroll
      for (int j2 = 0; j2 < 8; ++j2) {
        w0[j2]  = (short)f2b(v[j2]);
        w1v[j2] = (short)f2b(v[8 + j2]);
      }
      *(bf16x8*)&Bt[bn][bkc*16]     = w0;
      *(bf16x8*)&Bt[bn][bkc*16 + 8] = w1v;
    }
    __syncthreads();
#pragma unroll
    for (int fk = 0; fk < 2; ++fk) {
      bf16x8 a0 = *(const bf16x8*)&As[wm*32 +      lr][fk*32 + lk];
      bf16x8 a1 = *(const bf16x8*)&As[wm*32 + 16 + lr][fk*32 + lk];
      bf16x8 b0 = *(const bf16x8*)&Bt[wn*32 +      lr][fk*32 + lk];
      bf16x8 b1 = *(const bf16x8*)&Bt[wn*32 + 16 + lr][fk*32 + lk];
      acc[0][0] = __builtin_amdgcn_mfma_f32_16x16x32_bf16(a0, b0, acc[0][0], 0, 0, 0);
      acc[0][1] = __builtin_amdgcn_mfma_f32_16x16x32_bf16(a0, b1, acc[0][1], 0, 0, 0);
      acc[1][0] = __builtin_amdgcn_mfma_f32_16x16x32_bf16(a1, b0, acc[1][0], 0, 0, 0);
      acc[1][1] = __builtin_amdgcn_mfma_f32_16x16x32_bf16(a1, b1, acc[1][1], 0, 0, 0);
    }
    __syncthreads();
  }
#pragma unroll
  for (int fn = 0; fn < 2; ++fn) {
    int col = n0 + wn*32 + fn*16 + lr;
    float s1 = 0.f, s2 = 0.f;
#pragma unroll
    for (int fm = 0; fm < 2; ++fm) {
#pragma unroll
      for (int r = 0; r < 4; ++r) {
        int row = m0 + wm*32 + fm*16 + (l >> 4)*4 + r;
        float v = acc[fm][fn][r];
        if constexpr (sizeof(TO) == 4) out[(size_t)row*NOUT + col] = v;
        else                           out[(size_t)row*NOUT + col] = f2b(v);
        if (STATS) { s1 += v; s2 += v*v; }
      }
    }
    if (STATS) {
      s1 += __shfl_xor(s1, 16); s1 += __shfl_xor(s1, 32);
      s2 += __shfl_xor(s2, 16); s2 += __shfl_xor(s2, 32);
      if (l < 16) {
        atomicAdd(&stout[col], s1);
        atomicAdd(&stout[NOUT + col], s2);
      }
    }
  }
}

// ---------------------------------------------------------------- p_r helpers
__device__ __forceinline__ void comp_pr1(const float* p, int i, int j,
                                         const float* Wp1, const float* bp1,
                                         float pr1[3]) {
  float rx = p[j*3+0] - p[i*3+0];
  float ry = p[j*3+1] - p[i*3+1];
  float rz = p[j*3+2] - p[i*3+2];
#pragma unroll
  for (int c = 0; c < 3; ++c)
    pr1[c] = rx*Wp1[c] + ry*Wp1[3+c] + rz*Wp1[6+c] + bp1[c];
}

__device__ __forceinline__ void comp_prv(const float* p, int i, int j,
                                         const float* Wp1, const float* bp1,
                                         const float* gp, const float* bpp,
                                         const float* sp, float o3[3]) {
  float pr1[3];
  comp_pr1(p, i, j, Wp1, bp1, pr1);
#pragma unroll
  for (int c = 0; c < 3; ++c)
    o3[c] = fmaxf(bn_ap(pr1[c], sp, 3, c, INV_NK, gp[c], bpp[c]), 0.0f);
}

// ---------------------------------------------------------------- prstats device body
__device__ __forceinline__ void prstats_dev(char* smem,
    const float* __restrict__ p, const int* __restrict__ idx,
    const float* Wp1, const float* bp1, float* __restrict__ sp, int pb) {
  float s[3] = {0,0,0}, s2[3] = {0,0,0};
  for (int it = 0; it < 4; ++it) {
    int e = pb*1024 + it*256 + threadIdx.x;
    int i = e >> 4;
    int j = idx[e] & 8191;
    float pr1[3];
    comp_pr1(p, i, j, Wp1, bp1, pr1);
#pragma unroll
    for (int c = 0; c < 3; ++c) { s[c] += pr1[c]; s2[c] += pr1[c]*pr1[c]; }
  }
#pragma unroll
  for (int m = 1; m < 64; m <<= 1) {
#pragma unroll
    for (int c = 0; c < 3; ++c) {
      s[c]  += __shfl_xor(s[c],  m);
      s2[c] += __shfl_xor(s2[c], m);
    }
  }
  float (*red)[6] = (float(*)[6])smem;
  int wv = threadIdx.x >> 6, lane = threadIdx.x & 63;
  if (lane == 0) {
#pragma unroll
    for (int c = 0; c < 3; ++c) { red[wv][c] = s[c]; red[wv][3+c] = s2[c]; }
  }
  __syncthreads();
  if (threadIdx.x < 6) {
    float v = red[0][threadIdx.x] + red[1][threadIdx.x] +
              red[2][threadIdx.x] + red[3][threadIdx.x];
    atomicAdd(&sp[threadIdx.x], v);
  }
}

// ---------------------------------------------------------------- packed: mfgemm1 (512) || knn-full (2048)
__launch_bounds__(256)
__global__ void gemmknn_k(const float* __restrict__ x, const float* __restrict__ W_pa,
                          u16* __restrict__ t0, float* __restrict__ st0,
                          const float4* __restrict__ pp, int* __restrict__ idxo) {
  extern __shared__ char smem[];
  int b = blockIdx.x;
  if (b < 512)
    mfgemm_dev<float, u16, false, true>(smem, x, nullptr, nullptr, nullptr, 0.f,
                                        W_pa, t0, st0, 64, 256, b & 127, b >> 7);
  else
    knn_dev(smem, pp, idxo, b - 512);        // kb 0..2047 -> all 8192 queries
}

// ---------------------------------------------------------------- packed: mfgemm2 (512) || prstats (128)
__launch_bounds__(256)
__global__ void gemmpr_k(const u16* __restrict__ t0, const float* __restrict__ st0,
                         const float* __restrict__ g_pa, const float* __restrict__ b_pa,
                         const float* __restrict__ W1, u16* __restrict__ t1,
                         float* __restrict__ st1,
                         const float* __restrict__ p, const int* __restrict__ idx,
                         const float* __restrict__ Wp1, const float* __restrict__ bp1,
                         float* __restrict__ sp) {
  extern __shared__ char smem[];
  int b = blockIdx.x;
  if (b < 512)
    mfgemm_dev<u16, u16, true, true>(smem, t0, st0, g_pa, b_pa, INV_N,
                                     W1, t1, st1, 256, 256, b & 127, b >> 7);
  else
    prstats_dev(smem, p, idx, Wp1, bp1, sp, b - 512);
}

// ---------------------------------------------------------------- standalone mfgemm wrapper (W3 pass)
template<typename TA, typename TO, bool BNA, bool STATS>
__launch_bounds__(256)
__global__ void mfgemm_k(const TA* __restrict__ A, const float* __restrict__ st,
                         const float* __restrict__ g, const float* __restrict__ bb,
                         float inv_cnt,
                         const float* __restrict__ W, TO* __restrict__ out,
                         float* __restrict__ stout, int KA, int NOUT) {
  extern __shared__ char smem[];
  mfgemm_dev<TA, TO, BNA, STATS>(smem, A, st, g, bb, inv_cnt, W, out, stout,
                                 KA, NOUT, blockIdx.x, blockIdx.y);
}

// ---------------------------------------------------------------- fused Q/K/V MFMA (bf16 in/out, static smem)
__launch_bounds__(256)
__global__ void qkv_k(const u16* __restrict__ t1, const float* __restrict__ st,
                      const float* __restrict__ g1, const float* __restrict__ b1,
                      const float* __restrict__ Wq, const float* __restrict__ bq,
                      const float* __restrict__ Wk, const float* __restrict__ bk,
                      const float* __restrict__ Wv, const float* __restrict__ bv,
                      u16* __restrict__ xq, u16* __restrict__ xk, u16* __restrict__ xv) {
  __shared__ short As[64][72];
  __shared__ short Bt[3][64][72];
  __shared__ float lscl[256], lsft[256];
  int t = threadIdx.x;
  int m0 = blockIdx.x * 64, n0 = blockIdx.y * 64;
  {
    int e = t;
    float m = st[e] * INV_N;
    float var = st[256 + e] * INV_N - m*m;
    float sc = rsqrtf(var + 1e-5f) * g1[e];
    lscl[e] = sc; lsft[e] = b1[e] - m*sc;
  }
  __syncthreads();
  const f32x4 zero = {0.f, 0.f, 0.f, 0.f};
  f32x4 acc[3][2][2];
#pragma unroll
  for (int w = 0; w < 3; ++w)
#pragma unroll
    for (int i = 0; i < 2; ++i)
#pragma unroll
      for (int j = 0; j < 2; ++j) acc[w][i][j] = zero;
  int wv = t >> 6, l = t & 63;
  int wm = wv & 1, wn = wv >> 1;
  int lr = l & 15, lk = (l >> 4) * 8;
  int ra = t >> 4, qa = t & 15;
  int bn = t & 63, bkc = t >> 6;
  const float* Ws[3] = {Wq, Wk, Wv};
  for (int k0 = 0; k0 < 256; k0 += 64) {
#pragma unroll
    for (int rp = 0; rp < 4; ++rp) {
      int r = rp*16 + ra;
      short4 av = *(const short4*)(t1 + (size_t)(m0 + r)*256 + k0 + qa*4);
      short4 s;
#pragma unroll
      for (int jj = 0; jj < 4; ++jj) {
        int ch = k0 + qa*4 + jj;
        float v = fmaxf(fmaf(b2f(((u16*)&av)[jj]), lscl[ch], lsft[ch]), 0.f);
        ((u16*)&s)[jj] = f2b(v);
      }
      *(short4*)&As[r][qa*4] = s;
    }
#pragma unroll
    for (int w = 0; w < 3; ++w) {
      float v[16];
#pragma unroll
      for (int j2 = 0; j2 < 16; ++j2)
        v[j2] = Ws[w][(size_t)(k0 + bkc*16 + j2)*256 + n0 + bn];
      bf16x8 w0, w1v;
#pragma unroll
      for (int j2 = 0; j2 < 8; ++j2) {
        w0[j2]  = (short)f2b(v[j2]);
        w1v[j2] = (short)f2b(v[8 + j2]);
      }
      *(bf16x8*)&Bt[w][bn][bkc*16]     = w0;
      *(bf16x8*)&Bt[w][bn][bkc*16 + 8] = w1v;
    }
    __syncthreads();
#pragma unroll
    for (int fk = 0; fk < 2; ++fk) {
      bf16x8 a0 = *(const bf16x8*)&As[wm*32 +      lr][fk*32 + lk];
      bf16x8 a1 = *(const bf16x8*)&As[wm*32 + 16 + lr][fk*32 + lk];
#pragma unroll
      for (int w = 0; w < 3; ++w) {
        bf16x8 b0 = *(const bf16x8*)&Bt[w][wn*32 +      lr][fk*32 + lk];
        bf16x8 b1 = *(const bf16x8*)&Bt[w][wn*32 + 16 + lr][fk*32 + lk];
        acc[w][0][0] = __builtin_amdgcn_mfma_f32_16x16x32_bf16(a0, b0, acc[w][0][0], 0, 0, 0);
        acc[w][0][1] = __builtin_amdgcn_mfma_f32_16x16x32_bf16(a0, b1, acc[w][0][1], 0, 0, 0);
        acc[w][1][0] = __builtin_amdgcn_mfma_f32_16x16x32_bf16(a1, b0, acc[w][1][0], 0, 0, 0);
        acc[w][1][1] = __builtin_amdgcn_mfma_f32_16x16x32_bf16(a1, b1, acc[w][1][1], 0, 0, 0);
      }
    }
    __syncthreads();
  }
  u16* outs[3] = {xq, xk, xv};
  const float* bs[3] = {bq, bk, bv};
#pragma unroll
  for (int w = 0; w < 3; ++w) {
#pragma unroll
    for (int fn = 0; fn < 2; ++fn) {
      int col = n0 + wn*32 + fn*16 + lr;
      float bvv = bs[w][col];
#pragma unroll
      for (int fm = 0; fm < 2; ++fm) {
#pragma unroll
        for (int r = 0; r < 4; ++r) {
          int row = m0 + wm*32 + fm*16 + (l >> 4)*4 + r;
          outs[w][(size_t)row*256 + col] = f2b(acc[w][fm][fn][r] + bvv);
        }
      }
    }
  }
}

// ---------------------------------------------------------------- y stats -> partials (bf16 in)
__launch_bounds__(256)
__global__ void stats256_k(const u16* __restrict__ X, float* __restrict__ psy) {
  int c = threadIdx.x;
  int r0 = blockIdx.x * 32;
  float s1 = 0.f, s2 = 0.f;
  for (int r = 0; r < 32; ++r) {
    float v = b2f(X[(size_t)(r0 + r)*256 + c]);
    s1 += v; s2 += v*v;
  }
  psy[(size_t)blockIdx.x*512 + c]       = s1;
  psy[(size_t)blockIdx.x*512 + 256 + c] = s2;
}

// ---------------------------------------------------------------- stats of w -> partials
__launch_bounds__(256)
__global__ void wstats_k(const u16* __restrict__ xk, const u16* __restrict__ xq,
                         const float* __restrict__ p, const int* __restrict__ idx,
                         const float* Wp1, const float* bp1, const float* gp, const float* bpp,
                         const float* sp, const float* __restrict__ Wp2, const float* bp2,
                         float* __restrict__ pws) {
  __shared__ float prv[8][16][4];
  __shared__ int   jidx[8][16];
  int base = blockIdx.x * 8;
  int t = threadIdx.x;
  if (t < 128) {
    int pt = t >> 4, k = t & 15;
    int j = idx[(base + pt)*16 + k] & 8191;
    jidx[pt][k] = j;
    float o3[3];
    comp_prv(p, base + pt, j, Wp1, bp1, gp, bpp, sp, o3);
    prv[pt][k][0] = o3[0]; prv[pt][k][1] = o3[1]; prv[pt][k][2] = o3[2];
  }
  __syncthreads();
  int c = t;
  float wp0 = Wp2[c], wp1v = Wp2[256+c], wp2v = Wp2[512+c];
  float bbv = bp2[c];
  float s1 = 0.f, s2 = 0.f;
  for (int pt = 0; pt < 8; ++pt) {
    int i = base + pt;
    float xqv = b2f(xq[(size_t)i*256 + c]);
    u16 kvals[16];
#pragma unroll
    for (int k = 0; k < 16; ++k)
      kvals[k] = xk[(size_t)jidx[pt][k]*256 + c];
#pragma unroll
    for (int k = 0; k < 16; ++k) {
      float pr = prv[pt][k][0]*wp0 + prv[pt][k][1]*wp1v + prv[pt][k][2]*wp2v + bbv;
      float wval = b2f(kvals[k]) - xqv + pr;
      s1 += wval; s2 += wval*wval;
    }
  }
  pws[(size_t)blockIdx.x*512 + c]       = s1;
  pws[(size_t)blockIdx.x*512 + 256 + c] = s2;
}

// ---------------------------------------------------------------- w1gemm: gather + partial-store stats
__launch_bounds__(256)
__global__ void w1gemm_k(const u16* __restrict__ xk, const u16* __restrict__ xq,
                         const float* __restrict__ p, const int* __restrict__ idx,
                         const float* Wp1, const float* bp1, const float* gp, const float* bpp,
                         const float* sp, const float* __restrict__ Wp2, const float* bp2,
                         const float* sw, const float* gw1, const float* bw1,
                         const u16* __restrict__ Ww1t, const float* bww1,
                         u16* __restrict__ w1, float* __restrict__ pw1) {
  __shared__ short sA[64][264];
  __shared__ float prv[64][3];
  __shared__ int   jrow[64];
  __shared__ float sred[256];
  int t = threadIdx.x;
  int base4 = blockIdx.x * 4;
  if (t < 64) {
    int grow = blockIdx.x*64 + t;
    int j = idx[grow] & 8191;
    jrow[t] = j;
    float o3[3];
    comp_prv(p, grow >> 4, j, Wp1, bp1, gp, bpp, sp, o3);
    prv[t][0] = o3[0]; prv[t][1] = o3[1]; prv[t][2] = o3[2];
  }
  __syncthreads();
  {
    int o = t & 31, rs = t >> 5;
    int ch0 = o*8;
    int jr[8];
#pragma unroll
    for (int ii = 0; ii < 8; ++ii) jr[ii] = jrow[ii*8 + rs];
    bf16x8 kvv[8], qvv[8];
#pragma unroll
    for (int ii = 0; ii < 8; ++ii) {
      int r = ii*8 + rs;
      kvv[ii] = *(const bf16x8*)(xk + (size_t)jr[ii]*256 + ch0);
      qvv[ii] = *(const bf16x8*)(xq + (size_t)(base4 + (r >> 4))*256 + ch0);
    }
    float sclv[8], sftv[8], w0v[8], w1vv[8], w2v[8], b2v[8];
#pragma unroll
    for (int h = 0; h < 2; ++h) {
      float4 swm = *(const float4*)(sw + ch0 + h*4);
      float4 sws = *(const float4*)(sw + 256 + ch0 + h*4);
      float4 g4  = *(const float4*)(gw1 + ch0 + h*4);
      float4 bb4 = *(const float4*)(bw1 + ch0 + h*4);
      float4 p0v = *(const float4*)(Wp2 + ch0 + h*4);
      float4 p1v = *(const float4*)(Wp2 + 256 + ch0 + h*4);
      float4 p2v = *(const float4*)(Wp2 + 512 + ch0 + h*4);
      float4 bp4 = *(const float4*)(bp2 + ch0 + h*4);
      float mv[4] = {swm.x, swm.y, swm.z, swm.w};
      float sv[4] = {sws.x, sws.y, sws.z, sws.w};
      float gv[4] = {g4.x, g4.y, g4.z, g4.w};
      float bv[4] = {bb4.x, bb4.y, bb4.z, bb4.w};
      float a0[4] = {p0v.x, p0v.y, p0v.z, p0v.w};
      float a1[4] = {p1v.x, p1v.y, p1v.z, p1v.w};
      float a2[4] = {p2v.x, p2v.y, p2v.z, p2v.w};
      float a3[4] = {bp4.x, bp4.y, bp4.z, bp4.w};
#pragma unroll
      for (int jj = 0; jj < 4; ++jj) {
        int e = h*4 + jj;
        float m = mv[jj]*INV_NK;
        float var = sv[jj]*INV_NK - m*m;
        float sc = rsqrtf(var + 1e-5f)*gv[jj];
        sclv[e] = sc; sftv[e] = bv[jj] - m*sc;
        w0v[e] = a0[jj]; w1vv[e] = a1[jj]; w2v[e] = a2[jj]; b2v[e] = a3[jj];
      }
    }
#pragma unroll
    for (int ii = 0; ii < 8; ++ii) {
      int r = ii*8 + rs;
      float p0 = prv[r][0], p1 = prv[r][1], p2 = prv[r][2];
      bf16x8 av;
#pragma unroll
      for (int e = 0; e < 8; ++e) {
        float v = b2f((u16)kvv[ii][e]) - b2f((u16)qvv[ii][e])
                + p0*w0v[e] + p1*w1vv[e] + p2*w2v[e] + b2v[e];
        v = fmaxf(fmaf(v, sclv[e], sftv[e]), 0.f);
        av[e] = (short)f2b(v);
      }
      *(bf16x8*)&sA[r][ch0] = av;
    }
  }
  __syncthreads();
  const f32x4 zero = {0.f,0.f,0.f,0.f};
  f32x4 acc[2] = {zero, zero};
  int wv = t >> 6, l = t & 63;
  int lr = l & 15, hi = l >> 4;
#pragma unroll
  for (int k0 = 0; k0 < 8; ++k0) {
    int kb = k0*32 + hi*8;
    bf16x8 a  = *(const bf16x8*)&sA[wv*16 + lr][kb];
    bf16x8 b0 = *(const bf16x8*)(Ww1t + (size_t)lr*256      + kb);
    bf16x8 b1 = *(const bf16x8*)(Ww1t + (size_t)(16+lr)*256 + kb);
    acc[0] = __builtin_amdgcn_mfma_f32_16x16x32_bf16(a, b0, acc[0], 0, 0, 0);
    acc[1] = __builtin_amdgcn_mfma_f32_16x16x32_bf16(a, b1, acc[1], 0, 0, 0);
  }
#pragma unroll
  for (int fn = 0; fn < 2; ++fn) {
    int col = fn*16 + lr;
    float bv = bww1[col];
    float s1 = 0.f, s2 = 0.f;
#pragma unroll
    for (int r = 0; r < 4; ++r) {
      int grow = blockIdx.x*64 + wv*16 + hi*4 + r;
      float v = acc[fn][r] + bv;
      w1[(size_t)grow*32 + col] = f2b(v);
      s1 += v; s2 += v*v;
    }
    s1 += __shfl_xor(s1, 16); s1 += __shfl_xor(s1, 32);
    s2 += __shfl_xor(s2, 16); s2 += __shfl_xor(s2, 32);
    if (l < 16) { sred[(wv*2+fn)*16 + lr] = s1; sred[128 + (wv*2+fn)*16 + lr] = s2; }
  }
  __syncthreads();
  if (t < 32) {
    float a = 0.f, b = 0.f;
#pragma unroll
    for (int w2 = 0; w2 < 4; ++w2) {
      a += sred[(w2*2 + (t >> 4))*16 + (t & 15)];
      b += sred[128 + (w2*2 + (t >> 4))*16 + (t & 15)];
    }
    pw1[(size_t)blockIdx.x*64 + t]      = a;
    pw1[(size_t)blockIdx.x*64 + 32 + t] = b;
  }
}

// ---------------------------------------------------------------- aggr (1 query/block, proven)
__launch_bounds__(256)
__global__ void aggr_k(const u16* __restrict__ w1, const float* sw1,
                       const float* gw2, const float* bw2,
                       const float* __restrict__ Ww2, const float* bww2,
                       const u16* __restrict__ xv,
                       const float* __restrict__ p, const int* __restrict__ idx,
                       const float* Wp1, const float* bp1, const float* gp, const float* bpp,
                       const float* sp, const float* __restrict__ Wp2, const float* bp2,
                       u16* __restrict__ y) {
  __shared__ float lw1[16][32];
  __shared__ float lW2[32][32];
  __shared__ float sw2[16][33];
  __shared__ float prv[16][4];
  __shared__ int   jidx[16];
  int i = blockIdx.x, t = threadIdx.x;
  for (int e = t; e < 1024; e += 256) lW2[e >> 5][e & 31] = Ww2[e];
  for (int e = t; e < 512; e += 256) {
    int c32 = e & 31;
    float v = b2f(w1[(size_t)i*512 + e]);
    v = fmaxf(bn_ap(v, sw1, 32, c32, INV_NK, gw2[c32], bw2[c32]), 0.0f);
    lw1[e >> 5][c32] = v;
  }
  if (t < 16) jidx[t] = idx[i*16 + t] & 8191;
  __syncthreads();
  if (t < 16) {
    float o3[3];
    comp_prv(p, i, jidx[t], Wp1, bp1, gp, bpp, sp, o3);
    prv[t][0] = o3[0]; prv[t][1] = o3[1]; prv[t][2] = o3[2];
  }
  for (int e = t; e < 512; e += 256) {
    int k = e >> 5, c32 = e & 31;
    float a = bww2[c32];
#pragma unroll
    for (int j = 0; j < 32; ++j) a += lw1[k][j] * lW2[j][c32];
    sw2[k][c32] = a;
  }
  __syncthreads();
  if (t < 32) {
    float mx = -3.0e38f;
#pragma unroll
    for (int k = 0; k < 16; ++k) mx = fmaxf(mx, sw2[k][t]);
    float s = 0.f;
#pragma unroll
    for (int k = 0; k < 16; ++k) { float e2 = expf(sw2[k][t] - mx); sw2[k][t] = e2; s += e2; }
    float r = 1.0f / s;
#pragma unroll
    for (int k = 0; k < 16; ++k) sw2[k][t] *= r;
  }
  __syncthreads();
  int c = t;
  float wp0 = Wp2[c], wp1v = Wp2[256+c], wp2v = Wp2[512+c];
  float bbv = bp2[c];
  int c32 = c & 31;
  float acc = 0.f;
#pragma unroll
  for (int k = 0; k < 16; ++k) {
    int j = jidx[k];
    float pr = prv[k][0]*wp0 + prv[k][1]*wp1v + prv[k][2]*wp2v + bbv;
    float xvv = b2f(xv[(size_t)j*256 + c]);
    acc += (xvv + pr) * sw2[k][c32];
  }
  y[(size_t)i*256 + c] = f2b(acc);
}

// ---------------------------------------------------------------- epilogue (bf16 in)
__launch_bounds__(256)
__global__ void final_k(const u16* __restrict__ t0, const float* s0,
                        const float* g0, const float* b0,
                        const u16* __restrict__ t3, const float* s3,
                        const float* g3, const float* b3,
                        float* __restrict__ out) {
  int i = blockIdx.x, c = threadIdx.x;
  size_t off = (size_t)i*256 + c;
  float h0 = fmaxf(bn_ap(b2f(t0[off]), s0, 256, c, INV_N, g0[c], b0[c]), 0.0f);
  float v3 = bn_ap(b2f(t3[off]), s3, 256, c, INV_N, g3[c], b3[c]);
  out[24576 + off] = fmaxf(v3 + h0, 0.0f);
}

// ---------------------------------------------------------------- launch
extern "C" void kernel_launch(void* const* d_in, const int* in_sizes, int n_in,
                              void* d_out, int out_size, void* d_ws, size_t ws_size,
                              hipStream_t stream) {
  (void)in_sizes; (void)n_in; (void)out_size; (void)ws_size;
  const float* p    = (const float*)d_in[0];
  const float* x    = (const float*)d_in[1];
  const int*   o    = (const int*)  d_in[2];
  const float* W_pa = (const float*)d_in[3];
  const float* g_pa = (const float*)d_in[4];
  const float* b_pa = (const float*)d_in[5];
  const float* W1   = (const float*)d_in[6];
  const float* g1   = (const float*)d_in[7];
  const float* b1   = (const float*)d_in[8];
  const float* Wq   = (const float*)d_in[9];
  const float* bq   = (const float*)d_in[10];
  const float* Wk   = (const float*)d_in[11];
  const float* bk   = (const float*)d_in[12];
  const float* Wv   = (const float*)d_in[13];
  const float* bv   = (const float*)d_in[14];
  const float* Wp1  = (const float*)d_in[15];
  const float* bp1  = (const float*)d_in[16];
  const float* gp   = (const float*)d_in[17];
  const float* bpp  = (const float*)d_in[18];
  const float* Wp2  = (const float*)d_in[19];
  const float* bp2  = (const float*)d_in[20];
  const float* gw1  = (const float*)d_in[21];
  const float* bw1  = (const float*)d_in[22];
  const float* Ww1  = (const float*)d_in[23];
  const float* bww1 = (const float*)d_in[24];
  const float* gw2  = (const float*)d_in[25];
  const float* bw2  = (const float*)d_in[26];
  const float* Ww2  = (const float*)d_in[27];
  const float* bww2 = (const float*)d_in[28];
  const float* g2   = (const float*)d_in[29];
  const float* b2   = (const float*)d_in[30];
  const float* W3   = (const float*)d_in[31];
  const float* g3   = (const float*)d_in[32];
  const float* b3   = (const float*)d_in[33];

  // workspace layout (~34 MB)
  char* ws = (char*)d_ws;
  u16*   t0  = (u16*)  (ws + 0);          // [8192,256] bf16 (live til final_k)
  u16*   t1  = (u16*)  (ws + 4194304);    // [8192,256] bf16 (later: y)
  u16*   xq  = (u16*)  (ws + 8388608);    // [8192,256] bf16 (later: t3)
  u16*   xk  = (u16*)  (ws + 12582912);   // [8192,256] bf16
  u16*   xv  = (u16*)  (ws + 16777216);   // [8192,256] bf16
  u16*   w1  = (u16*)  (ws + 20971520);   // [131072,32] bf16 (8 MB)
  int*   idx = (int*)  (ws + 29360128);   // [8192,16] i32
  float* st  = (float*)(ws + 29884416);   // stats block (16 KB)
  u16*   Ww1t= (u16*)  (ws + 29900800);   // [32][256] bf16 (16 KB)
  float* pw1 = (float*)(ws + 30408704);   // [2048][64] partials (512 KB)
  float* pws = (float*)(ws + 30932992);   // [1024][512] partials (2 MB)
  float* psy = (float*)(ws + 33030144);   // [256][512] partials (512 KB)
  u16*   y   = t1;                        // aggr output (t1 dead after qkv)
  u16*   t3  = xq;                        // aliases xq (dead after w1 stage)
  float4* pp = (float4*)(ws + 20971520);  // aliases w1 (knn finishes first)
  // st offsets: s0=0, s1=512, sw=1024, sy=1536, s3=2048, sw1=2560, sp=2624

  prep_k<<<96, 256, 0, stream>>>(p, o, Ww1, pp, Ww1t, st, (float*)d_out);

  gemmknn_k<<<2560, 256, 20480, stream>>>(x, W_pa, t0, st + 0, pp, idx);

  gemmpr_k<<<640, 256, 20480, stream>>>(t0, st + 0, g_pa, b_pa, W1, t1, st + 512,
                                        p, idx, Wp1, bp1, st + 2624);

  qkv_k<<<dim3(128, 4), 256, 0, stream>>>(
      t1, st + 512, g1, b1, Wq, bq, Wk, bk, Wv, bv, xq, xk, xv);

  wstats_k<<<1024, 256, 0, stream>>>(xk, xq, p, idx, Wp1, bp1, gp, bpp,
                                     st + 2624, Wp2, bp2, pws);
  red_k<1024, 4><<<32, 256, 0, stream>>>(pws, st + 1024, 512);

  w1gemm_k<<<2048, 256, 0, stream>>>(xk, xq, p, idx, Wp1, bp1, gp, bpp,
                                     st + 2624, Wp2, bp2, st + 1024,
                                     gw1, bw1, Ww1t, bww1, w1, pw1);
  red_k<2048, 16><<<16, 256, 0, stream>>>(pw1, st + 2560, 64);

  aggr_k<<<8192, 256, 0, stream>>>(w1, st + 2560, gw2, bw2, Ww2, bww2, xv,
                                   p, idx, Wp1, bp1, gp, bpp, st + 2624,
                                   Wp2, bp2, y);
  stats256_k<<<256, 256, 0, stream>>>(y, psy);
  red_k<256, 2><<<16, 256, 0, stream>>>(psy, st + 1536, 512);

  mfgemm_k<u16, u16, true, true><<<dim3(128, 4), 256, 20480, stream>>>(
      y, st + 1536, g2, b2, INV_N, W3, t3, st + 2048, 256, 256);

  final_k<<<8192, 256, 0, stream>>>(t0, st + 0, g_pa, b_pa,
                                    t3, st + 2048, g3, b3, (float*)d_out);
}

// Round 28
// 182.252 us; speedup vs baseline: 1.0680x; 1.0052x over previous
//
#include <hip/hip_runtime.h>
#include <hip/hip_bf16.h>

// N=8192, K=16, CIN=64, C=256, S=8, C/S=32 ; float tensors are float32.
#define INV_N  (1.0f/8192.0f)
#define INV_NK (1.0f/131072.0f)

typedef __attribute__((ext_vector_type(8))) short bf16x8;
typedef __attribute__((ext_vector_type(4))) float f32x4;
typedef unsigned short u16;

__device__ __forceinline__ u16 f2b(float f) {   // f32 -> bf16 RNE
  unsigned u = __float_as_uint(f);
  return (u16)((u + 0x7FFFu + ((u >> 16) & 1u)) >> 16);
}
__device__ __forceinline__ float b2f(u16 u) {
  return __uint_as_float(((unsigned)u) << 16);
}

__device__ __forceinline__ float bn_ap(float v, const float* st, int C, int ch,
                                       float inv, float g, float b) {
  float m = st[ch] * inv;
  float var = st[C + ch] * inv - m * m;
  return (v - m) * rsqrtf(var + 1e-5f) * g + b;
}

// ---------------------------------------------------------------- prep
__launch_bounds__(256)
__global__ void prep_k(const float* __restrict__ p, const int* __restrict__ o,
                       const float* __restrict__ Ww1,
                       float4* __restrict__ pp, u16* __restrict__ Ww1t,
                       float* __restrict__ st, float* __restrict__ out) {
  int b = blockIdx.x, t = threadIdx.x;
  int e = b*256 + t;
  if (b < 16) st[b*256 + t] = 0.f;
  if (e < 24576) out[e] = p[e];
  if (e == 0) out[24576 + 2097152] = (float)o[0];
  if (e < 8192) {
    float x = p[e*3+0], y = p[e*3+1], z = p[e*3+2];
    pp[e] = make_float4(x, y, z, (x*x + y*y) + z*z);
  }
  if (b >= 88) {
    int q = (b - 88)*1024 + t*4;
#pragma unroll
    for (int ii = 0; ii < 4; ++ii) {
      int e2 = q + ii;
      int k = e2 >> 5, n = e2 & 31;
      Ww1t[n*256 + k] = f2b(Ww1[e2]);
    }
  }
}

// ---------------------------------------------------------------- generic partial-sum reduce
template<int ROWS, int SPLIT>
__launch_bounds__(256)
__global__ void red_k(const float* __restrict__ part, float* __restrict__ outp,
                      int width) {
  int ncg = width >> 6;
  int cg = blockIdx.x % ncg, sp = blockIdx.x / ncg;
  int lane = threadIdx.x & 63, chunk = threadIdx.x >> 6;
  int c = cg*64 + lane;
  constexpr int R  = ROWS / SPLIT;
  constexpr int RC = R / 4;
  float s = 0.f;
  int i0 = sp*R + chunk*RC;
#pragma unroll 4
  for (int i = i0; i < i0 + RC; ++i) s += part[(size_t)i*width + c];
  __shared__ float red[4][64];
  red[chunk][lane] = s;
  __syncthreads();
  if (threadIdx.x < 64) {
    float v = red[0][lane] + red[1][lane] + red[2][lane] + red[3][lane];
    if (SPLIT == 1) outp[c] = v;
    else atomicAdd(&outp[c], v);
  }
}

// ---------------------------------------------------------------- KNN v10: 1 query/wave, med3 insert, 3-fma dist (|q|^2 dropped)
__device__ __forceinline__ void knn_dev(char* smem, const float4* __restrict__ pp,
                                        int* __restrict__ idxo, int kb) {
  float4* buf = (float4*)smem;                 // 1024 float4 = 16 KB
  int t = threadIdx.x;
  int wave = t >> 6, lane = t & 63;
  int q = kb*4 + wave;
  float4 qv = pp[q];
  float m2x = -2.0f*qv.x, m2y = -2.0f*qv.y, m2z = -2.0f*qv.z;
  const float BIG = __uint_as_float(0x7F7FFFFFu);
  float d[3];
#pragma unroll
  for (int s = 0; s < 3; ++s) d[s] = BIG;
  for (int ch = 0; ch < 8; ++ch) {
#pragma unroll
    for (int s = 0; s < 4; ++s)
      buf[s*256 + t] = pp[ch*1024 + s*256 + t];
    __syncthreads();
#pragma unroll 4
    for (int it = 0; it < 16; ++it) {
      int jl = it*64 + lane;
      float4 c = buf[jl];
      int j = ch*1024 + jl;
      // per-query ranking is invariant to +|q|^2, so use
      // d2' = |c|^2 - 2 q.c  (pure 3-fma chain)
      float d2 = __fmaf_rn(m2x, c.x,
                 __fmaf_rn(m2y, c.y,
                 __fmaf_rn(m2z, c.z, c.w)));
      float pk = __uint_as_float((__float_as_uint(d2) & 0xFFFFE000u) | (unsigned)j);
      d[2] = __builtin_amdgcn_fmed3f(pk, d[1], d[2]);
      d[1] = __builtin_amdgcn_fmed3f(pk, d[0], d[1]);
      d[0] = fminf(d[0], pk);
    }
    __syncthreads();
  }
  for (int r = 0; r < 16; ++r) {
    float bd = d[0];
#pragma unroll
    for (int m = 1; m < 64; m <<= 1)
      bd = fminf(bd, __shfl_xor(bd, m));
    if (lane == 0) idxo[q*16 + r] = (int)(__float_as_uint(bd) & 0x1FFFu);
    if (d[0] == bd) { d[0] = d[1]; d[1] = d[2]; d[2] = BIG; }
  }
}

// ---------------------------------------------------------------- MFMA GEMM device body (20480 B smem)
template<typename TA, typename TO, bool BNA, bool STATS>
__device__ __forceinline__ void mfgemm_dev(char* smem,
    const TA* __restrict__ A, const float* __restrict__ st,
    const float* __restrict__ g, const float* __restrict__ bb, float inv_cnt,
    const float* __restrict__ W, TO* __restrict__ out,
    float* __restrict__ stout, int KA, int NOUT, int bm, int bn_) {
  short (*As)[72] = (short(*)[72])smem;
  short (*Bt)[72] = (short(*)[72])(smem + 9216);
  float* lscl = (float*)(smem + 18432);
  float* lsft = (float*)(smem + 19456);
  int t = threadIdx.x;
  int m0 = bm * 64, n0 = bn_ * 64;
  if (BNA) {
    for (int e = t; e < KA; e += 256) {
      float m = st[e] * inv_cnt;
      float var = st[KA + e] * inv_cnt - m*m;
      float sc = rsqrtf(var + 1e-5f) * g[e];
      lscl[e] = sc; lsft[e] = bb[e] - m*sc;
    }
    __syncthreads();
  }
  const f32x4 zero = {0.f, 0.f, 0.f, 0.f};
  f32x4 acc[2][2] = {{zero, zero}, {zero, zero}};
  int wv = t >> 6, l = t & 63;
  int wm = wv & 1, wn = wv >> 1;
  int lr = l & 15, lk = (l >> 4) * 8;
  int ra = t >> 4, qa = t & 15;
  int bn = t & 63, bkc = t >> 6;
  for (int k0 = 0; k0 < KA; k0 += 64) {
#pragma unroll
    for (int rp = 0; rp < 4; ++rp) {
      int r = rp*16 + ra;
      float vv[4];
      if constexpr (sizeof(TA) == 4) {
        float4 av = *(const float4*)((const float*)A + (size_t)(m0 + r)*KA + k0 + qa*4);
        vv[0] = av.x; vv[1] = av.y; vv[2] = av.z; vv[3] = av.w;
      } else {
        short4 av = *(const short4*)((const u16*)A + (size_t)(m0 + r)*KA + k0 + qa*4);
#pragma unroll
        for (int jj = 0; jj < 4; ++jj) vv[jj] = b2f(((u16*)&av)[jj]);
      }
      short4 s;
#pragma unroll
      for (int jj = 0; jj < 4; ++jj) {
        float v = vv[jj];
        if (BNA) { int ch = k0 + qa*4 + jj; v = fmaxf(fmaf(v, lscl[ch], lsft[ch]), 0.f); }
        ((u16*)&s)[jj] = f2b(v);
      }
      *(short4*)&As[r][qa*4] = s;
    }
    {
      float v[16];
#pragma unroll
      for (int j2 = 0; j2 < 16; ++j2)
        v[j2] = W[(size_t)(k0 + bkc*16 + j2)*NOUT + n0 + bn];
      bf16x8 w0, w1v;
#pragma unroll
      for (int j2 = 0; j2 < 8; ++j2) {
        w0[j2]  = (short)f2b(v[j2]);
        w1v[j2] = (short)f2b(v[8 + j2]);
      }
      *(bf16x8*)&Bt[bn][bkc*16]     = w0;
      *(bf16x8*)&Bt[bn][bkc*16 + 8] = w1v;
    }
    __syncthreads();
#pragma unroll
    for (int fk = 0; fk < 2; ++fk) {
      bf16x8 a0 = *(const bf16x8*)&As[wm*32 +      lr][fk*32 + lk];
      bf16x8 a1 = *(const bf16x8*)&As[wm*32 + 16 + lr][fk*32 + lk];
      bf16x8 b0 = *(const bf16x8*)&Bt[wn*32 +      lr][fk*32 + lk];
      bf16x8 b1 = *(const bf16x8*)&Bt[wn*32 + 16 + lr][fk*32 + lk];
      acc[0][0] = __builtin_amdgcn_mfma_f32_16x16x32_bf16(a0, b0, acc[0][0], 0, 0, 0);
      acc[0][1] = __builtin_amdgcn_mfma_f32_16x16x32_bf16(a0, b1, acc[0][1], 0, 0, 0);
      acc[1][0] = __builtin_amdgcn_mfma_f32_16x16x32_bf16(a1, b0, acc[1][0], 0, 0, 0);
      acc[1][1] = __builtin_amdgcn_mfma_f32_16x16x32_bf16(a1, b1, acc[1][1], 0, 0, 0);
    }
    __syncthreads();
  }
#pragma unroll
  for (int fn = 0; fn < 2; ++fn) {
    int col = n0 + wn*32 + fn*16 + lr;
    float s1 = 0.f, s2 = 0.f;
#pragma unroll
    for (int fm = 0; fm < 2; ++fm) {
#pragma unroll
      for (int r = 0; r < 4; ++r) {
        int row = m0 + wm*32 + fm*16 + (l >> 4)*4 + r;
        float v = acc[fm][fn][r];
        if constexpr (sizeof(TO) == 4) out[(size_t)row*NOUT + col] = v;
        else                           out[(size_t)row*NOUT + col] = f2b(v);
        if (STATS) { s1 += v; s2 += v*v; }
      }
    }
    if (STATS) {
      s1 += __shfl_xor(s1, 16); s1 += __shfl_xor(s1, 32);
      s2 += __shfl_xor(s2, 16); s2 += __shfl_xor(s2, 32);
      if (l < 16) {
        atomicAdd(&stout[col], s1);
        atomicAdd(&stout[NOUT + col], s2);
      }
    }
  }
}

// ---------------------------------------------------------------- p_r helpers
__device__ __forceinline__ void comp_pr1(const float* p, int i, int j,
                                         const float* Wp1, const float* bp1,
                                         float pr1[3]) {
  float rx = p[j*3+0] - p[i*3+0];
  float ry = p[j*3+1] - p[i*3+1];
  float rz = p[j*3+2] - p[i*3+2];
#pragma unroll
  for (int c = 0; c < 3; ++c)
    pr1[c] = rx*Wp1[c] + ry*Wp1[3+c] + rz*Wp1[6+c] + bp1[c];
}

__device__ __forceinline__ void comp_prv(const float* p, int i, int j,
                                         const float* Wp1, const float* bp1,
                                         const float* gp, const float* bpp,
                                         const float* sp, float o3[3]) {
  float pr1[3];
  comp_pr1(p, i, j, Wp1, bp1, pr1);
#pragma unroll
  for (int c = 0; c < 3; ++c)
    o3[c] = fmaxf(bn_ap(pr1[c], sp, 3, c, INV_NK, gp[c], bpp[c]), 0.0f);
}

// ---------------------------------------------------------------- prstats device body
__device__ __forceinline__ void prstats_dev(char* smem,
    const float* __restrict__ p, const int* __restrict__ idx,
    const float* Wp1, const float* bp1, float* __restrict__ sp, int pb) {
  float s[3] = {0,0,0}, s2[3] = {0,0,0};
  for (int it = 0; it < 4; ++it) {
    int e = pb*1024 + it*256 + threadIdx.x;
    int i = e >> 4;
    int j = idx[e] & 8191;
    float pr1[3];
    comp_pr1(p, i, j, Wp1, bp1, pr1);
#pragma unroll
    for (int c = 0; c < 3; ++c) { s[c] += pr1[c]; s2[c] += pr1[c]*pr1[c]; }
  }
#pragma unroll
  for (int m = 1; m < 64; m <<= 1) {
#pragma unroll
    for (int c = 0; c < 3; ++c) {
      s[c]  += __shfl_xor(s[c],  m);
      s2[c] += __shfl_xor(s2[c], m);
    }
  }
  float (*red)[6] = (float(*)[6])smem;
  int wv = threadIdx.x >> 6, lane = threadIdx.x & 63;
  if (lane == 0) {
#pragma unroll
    for (int c = 0; c < 3; ++c) { red[wv][c] = s[c]; red[wv][3+c] = s2[c]; }
  }
  __syncthreads();
  if (threadIdx.x < 6) {
    float v = red[0][threadIdx.x] + red[1][threadIdx.x] +
              red[2][threadIdx.x] + red[3][threadIdx.x];
    atomicAdd(&sp[threadIdx.x], v);
  }
}

// ---------------------------------------------------------------- packed: mfgemm1 (512) || knn-full (2048)
__launch_bounds__(256)
__global__ void gemmknn_k(const float* __restrict__ x, const float* __restrict__ W_pa,
                          u16* __restrict__ t0, float* __restrict__ st0,
                          const float4* __restrict__ pp, int* __restrict__ idxo) {
  extern __shared__ char smem[];
  int b = blockIdx.x;
  if (b < 512)
    mfgemm_dev<float, u16, false, true>(smem, x, nullptr, nullptr, nullptr, 0.f,
                                        W_pa, t0, st0, 64, 256, b & 127, b >> 7);
  else
    knn_dev(smem, pp, idxo, b - 512);        // kb 0..2047 -> all 8192 queries
}

// ---------------------------------------------------------------- packed: mfgemm2 (512) || prstats (128)
__launch_bounds__(256)
__global__ void gemmpr_k(const u16* __restrict__ t0, const float* __restrict__ st0,
                         const float* __restrict__ g_pa, const float* __restrict__ b_pa,
                         const float* __restrict__ W1, u16* __restrict__ t1,
                         float* __restrict__ st1,
                         const float* __restrict__ p, const int* __restrict__ idx,
                         const float* __restrict__ Wp1, const float* __restrict__ bp1,
                         float* __restrict__ sp) {
  extern __shared__ char smem[];
  int b = blockIdx.x;
  if (b < 512)
    mfgemm_dev<u16, u16, true, true>(smem, t0, st0, g_pa, b_pa, INV_N,
                                     W1, t1, st1, 256, 256, b & 127, b >> 7);
  else
    prstats_dev(smem, p, idx, Wp1, bp1, sp, b - 512);
}

// ---------------------------------------------------------------- standalone mfgemm wrapper (W3 pass)
template<typename TA, typename TO, bool BNA, bool STATS>
__launch_bounds__(256)
__global__ void mfgemm_k(const TA* __restrict__ A, const float* __restrict__ st,
                         const float* __restrict__ g, const float* __restrict__ bb,
                         float inv_cnt,
                         const float* __restrict__ W, TO* __restrict__ out,
                         float* __restrict__ stout, int KA, int NOUT) {
  extern __shared__ char smem[];
  mfgemm_dev<TA, TO, BNA, STATS>(smem, A, st, g, bb, inv_cnt, W, out, stout,
                                 KA, NOUT, blockIdx.x, blockIdx.y);
}

// ---------------------------------------------------------------- fused Q/K/V MFMA (bf16 in/out, static smem)
__launch_bounds__(256)
__global__ void qkv_k(const u16* __restrict__ t1, const float* __restrict__ st,
                      const float* __restrict__ g1, const float* __restrict__ b1,
                      const float* __restrict__ Wq, const float* __restrict__ bq,
                      const float* __restrict__ Wk, const float* __restrict__ bk,
                      const float* __restrict__ Wv, const float* __restrict__ bv,
                      u16* __restrict__ xq, u16* __restrict__ xk, u16* __restrict__ xv) {
  __shared__ short As[64][72];
  __shared__ short Bt[3][64][72];
  __shared__ float lscl[256], lsft[256];
  int t = threadIdx.x;
  int m0 = blockIdx.x * 64, n0 = blockIdx.y * 64;
  {
    int e = t;
    float m = st[e] * INV_N;
    float var = st[256 + e] * INV_N - m*m;
    float sc = rsqrtf(var + 1e-5f) * g1[e];
    lscl[e] = sc; lsft[e] = b1[e] - m*sc;
  }
  __syncthreads();
  const f32x4 zero = {0.f, 0.f, 0.f, 0.f};
  f32x4 acc[3][2][2];
#pragma unroll
  for (int w = 0; w < 3; ++w)
#pragma unroll
    for (int i = 0; i < 2; ++i)
#pragma unroll
      for (int j = 0; j < 2; ++j) acc[w][i][j] = zero;
  int wv = t >> 6, l = t & 63;
  int wm = wv & 1, wn = wv >> 1;
  int lr = l & 15, lk = (l >> 4) * 8;
  int ra = t >> 4, qa = t & 15;
  int bn = t & 63, bkc = t >> 6;
  const float* Ws[3] = {Wq, Wk, Wv};
  for (int k0 = 0; k0 < 256; k0 += 64) {
#pragma unroll
    for (int rp = 0; rp < 4; ++rp) {
      int r = rp*16 + ra;
      short4 av = *(const short4*)(t1 + (size_t)(m0 + r)*256 + k0 + qa*4);
      short4 s;
#pragma unroll
      for (int jj = 0; jj < 4; ++jj) {
        int ch = k0 + qa*4 + jj;
        float v = fmaxf(fmaf(b2f(((u16*)&av)[jj]), lscl[ch], lsft[ch]), 0.f);
        ((u16*)&s)[jj] = f2b(v);
      }
      *(short4*)&As[r][qa*4] = s;
    }
#pragma unroll
    for (int w = 0; w < 3; ++w) {
      float v[16];
#pragma unroll
      for (int j2 = 0; j2 < 16; ++j2)
        v[j2] = Ws[w][(size_t)(k0 + bkc*16 + j2)*256 + n0 + bn];
      bf16x8 w0, w1v;
#pragma unroll
      for (int j2 = 0; j2 < 8; ++j2) {
        w0[j2]  = (short)f2b(v[j2]);
        w1v[j2] = (short)f2b(v[8 + j2]);
      }
      *(bf16x8*)&Bt[w][bn][bkc*16]     = w0;
      *(bf16x8*)&Bt[w][bn][bkc*16 + 8] = w1v;
    }
    __syncthreads();
#pragma unroll
    for (int fk = 0; fk < 2; ++fk) {
      bf16x8 a0 = *(const bf16x8*)&As[wm*32 +      lr][fk*32 + lk];
      bf16x8 a1 = *(const bf16x8*)&As[wm*32 + 16 + lr][fk*32 + lk];
#pragma unroll
      for (int w = 0; w < 3; ++w) {
        bf16x8 b0 = *(const bf16x8*)&Bt[w][wn*32 +      lr][fk*32 + lk];
        bf16x8 b1 = *(const bf16x8*)&Bt[w][wn*32 + 16 + lr][fk*32 + lk];
        acc[w][0][0] = __builtin_amdgcn_mfma_f32_16x16x32_bf16(a0, b0, acc[w][0][0], 0, 0, 0);
        acc[w][0][1] = __builtin_amdgcn_mfma_f32_16x16x32_bf16(a0, b1, acc[w][0][1], 0, 0, 0);
        acc[w][1][0] = __builtin_amdgcn_mfma_f32_16x16x32_bf16(a1, b0, acc[w][1][0], 0, 0, 0);
        acc[w][1][1] = __builtin_amdgcn_mfma_f32_16x16x32_bf16(a1, b1, acc[w][1][1], 0, 0, 0);
      }
    }
    __syncthreads();
  }
  u16* outs[3] = {xq, xk, xv};
  const float* bs[3] = {bq, bk, bv};
#pragma unroll
  for (int w = 0; w < 3; ++w) {
#pragma unroll
    for (int fn = 0; fn < 2; ++fn) {
      int col = n0 + wn*32 + fn*16 + lr;
      float bvv = bs[w][col];
#pragma unroll
      for (int fm = 0; fm < 2; ++fm) {
#pragma unroll
        for (int r = 0; r < 4; ++r) {
          int row = m0 + wm*32 + fm*16 + (l >> 4)*4 + r;
          outs[w][(size_t)row*256 + col] = f2b(acc[w][fm][fn][r] + bvv);
        }
      }
    }
  }
}

// ---------------------------------------------------------------- y stats -> partials (bf16 in)
__launch_bounds__(256)
__global__ void stats256_k(const u16* __restrict__ X, float* __restrict__ psy) {
  int c = threadIdx.x;
  int r0 = blockIdx.x * 32;
  float s1 = 0.f, s2 = 0.f;
  for (int r = 0; r < 32; ++r) {
    float v = b2f(X[(size_t)(r0 + r)*256 + c]);
    s1 += v; s2 += v*v;
  }
  psy[(size_t)blockIdx.x*512 + c]       = s1;
  psy[(size_t)blockIdx.x*512 + 256 + c] = s2;
}

// ---------------------------------------------------------------- stats of w -> partials
__launch_bounds__(256)
__global__ void wstats_k(const u16* __restrict__ xk, const u16* __restrict__ xq,
                         const float* __restrict__ p, const int* __restrict__ idx,
                         const float* Wp1, const float* bp1, const float* gp, const float* bpp,
                         const float* sp, const float* __restrict__ Wp2, const float* bp2,
                         float* __restrict__ pws) {
  __shared__ float prv[8][16][4];
  __shared__ int   jidx[8][16];
  int base = blockIdx.x * 8;
  int t = threadIdx.x;
  if (t < 128) {
    int pt = t >> 4, k = t & 15;
    int j = idx[(base + pt)*16 + k] & 8191;
    jidx[pt][k] = j;
    float o3[3];
    comp_prv(p, base + pt, j, Wp1, bp1, gp, bpp, sp, o3);
    prv[pt][k][0] = o3[0]; prv[pt][k][1] = o3[1]; prv[pt][k][2] = o3[2];
  }
  __syncthreads();
  int c = t;
  float wp0 = Wp2[c], wp1v = Wp2[256+c], wp2v = Wp2[512+c];
  float bbv = bp2[c];
  float s1 = 0.f, s2 = 0.f;
  for (int pt = 0; pt < 8; ++pt) {
    int i = base + pt;
    float xqv = b2f(xq[(size_t)i*256 + c]);
    u16 kvals[16];
#pragma unroll
    for (int k = 0; k < 16; ++k)
      kvals[k] = xk[(size_t)jidx[pt][k]*256 + c];
#pragma unroll
    for (int k = 0; k < 16; ++k) {
      float pr = prv[pt][k][0]*wp0 + prv[pt][k][1]*wp1v + prv[pt][k][2]*wp2v + bbv;
      float wval = b2f(kvals[k]) - xqv + pr;
      s1 += wval; s2 += wval*wval;
    }
  }
  pws[(size_t)blockIdx.x*512 + c]       = s1;
  pws[(size_t)blockIdx.x*512 + 256 + c] = s2;
}

// ---------------------------------------------------------------- w1gemm: gather + partial-store stats
__launch_bounds__(256)
__global__ void w1gemm_k(const u16* __restrict__ xk, const u16* __restrict__ xq,
                         const float* __restrict__ p, const int* __restrict__ idx,
                         const float* Wp1, const float* bp1, const float* gp, const float* bpp,
                         const float* sp, const float* __restrict__ Wp2, const float* bp2,
                         const float* sw, const float* gw1, const float* bw1,
                         const u16* __restrict__ Ww1t, const float* bww1,
                         u16* __restrict__ w1, float* __restrict__ pw1) {
  __shared__ short sA[64][264];
  __shared__ float prv[64][3];
  __shared__ int   jrow[64];
  __shared__ float sred[256];
  int t = threadIdx.x;
  int base4 = blockIdx.x * 4;
  if (t < 64) {
    int grow = blockIdx.x*64 + t;
    int j = idx[grow] & 8191;
    jrow[t] = j;
    float o3[3];
    comp_prv(p, grow >> 4, j, Wp1, bp1, gp, bpp, sp, o3);
    prv[t][0] = o3[0]; prv[t][1] = o3[1]; prv[t][2] = o3[2];
  }
  __syncthreads();
  {
    int o = t & 31, rs = t >> 5;
    int ch0 = o*8;
    int jr[8];
#pragma unroll
    for (int ii = 0; ii < 8; ++ii) jr[ii] = jrow[ii*8 + rs];
    bf16x8 kvv[8], qvv[8];
#pragma unroll
    for (int ii = 0; ii < 8; ++ii) {
      int r = ii*8 + rs;
      kvv[ii] = *(const bf16x8*)(xk + (size_t)jr[ii]*256 + ch0);
      qvv[ii] = *(const bf16x8*)(xq + (size_t)(base4 + (r >> 4))*256 + ch0);
    }
    float sclv[8], sftv[8], w0v[8], w1vv[8], w2v[8], b2v[8];
#pragma unroll
    for (int h = 0; h < 2; ++h) {
      float4 swm = *(const float4*)(sw + ch0 + h*4);
      float4 sws = *(const float4*)(sw + 256 + ch0 + h*4);
      float4 g4  = *(const float4*)(gw1 + ch0 + h*4);
      float4 bb4 = *(const float4*)(bw1 + ch0 + h*4);
      float4 p0v = *(const float4*)(Wp2 + ch0 + h*4);
      float4 p1v = *(const float4*)(Wp2 + 256 + ch0 + h*4);
      float4 p2v = *(const float4*)(Wp2 + 512 + ch0 + h*4);
      float4 bp4 = *(const float4*)(bp2 + ch0 + h*4);
      float mv[4] = {swm.x, swm.y, swm.z, swm.w};
      float sv[4] = {sws.x, sws.y, sws.z, sws.w};
      float gv[4] = {g4.x, g4.y, g4.z, g4.w};
      float bv[4] = {bb4.x, bb4.y, bb4.z, bb4.w};
      float a0[4] = {p0v.x, p0v.y, p0v.z, p0v.w};
      float a1[4] = {p1v.x, p1v.y, p1v.z, p1v.w};
      float a2[4] = {p2v.x, p2v.y, p2v.z, p2v.w};
      float a3[4] = {bp4.x, bp4.y, bp4.z, bp4.w};
#pragma unroll
      for (int jj = 0; jj < 4; ++jj) {
        int e = h*4 + jj;
        float m = mv[jj]*INV_NK;
        float var = sv[jj]*INV_NK - m*m;
        float sc = rsqrtf(var + 1e-5f)*gv[jj];
        sclv[e] = sc; sftv[e] = bv[jj] - m*sc;
        w0v[e] = a0[jj]; w1vv[e] = a1[jj]; w2v[e] = a2[jj]; b2v[e] = a3[jj];
      }
    }
#pragma unroll
    for (int ii = 0; ii < 8; ++ii) {
      int r = ii*8 + rs;
      float p0 = prv[r][0], p1 = prv[r][1], p2 = prv[r][2];
      bf16x8 av;
#pragma unroll
      for (int e = 0; e < 8; ++e) {
        float v = b2f((u16)kvv[ii][e]) - b2f((u16)qvv[ii][e])
                + p0*w0v[e] + p1*w1vv[e] + p2*w2v[e] + b2v[e];
        v = fmaxf(fmaf(v, sclv[e], sftv[e]), 0.f);
        av[e] = (short)f2b(v);
      }
      *(bf16x8*)&sA[r][ch0] = av;
    }
  }
  __syncthreads();
  const f32x4 zero = {0.f,0.f,0.f,0.f};
  f32x4 acc[2] = {zero, zero};
  int wv = t >> 6, l = t & 63;
  int lr = l & 15, hi = l >> 4;
#pragma unroll
  for (int k0 = 0; k0 < 8; ++k0) {
    int kb = k0*32 + hi*8;
    bf16x8 a  = *(const bf16x8*)&sA[wv*16 + lr][kb];
    bf16x8 b0 = *(const bf16x8*)(Ww1t + (size_t)lr*256      + kb);
    bf16x8 b1 = *(const bf16x8*)(Ww1t + (size_t)(16+lr)*256 + kb);
    acc[0] = __builtin_amdgcn_mfma_f32_16x16x32_bf16(a, b0, acc[0], 0, 0, 0);
    acc[1] = __builtin_amdgcn_mfma_f32_16x16x32_bf16(a, b1, acc[1], 0, 0, 0);
  }
#pragma unroll
  for (int fn = 0; fn < 2; ++fn) {
    int col = fn*16 + lr;
    float bv = bww1[col];
    float s1 = 0.f, s2 = 0.f;
#pragma unroll
    for (int r = 0; r < 4; ++r) {
      int grow = blockIdx.x*64 + wv*16 + hi*4 + r;
      float v = acc[fn][r] + bv;
      w1[(size_t)grow*32 + col] = f2b(v);
      s1 += v; s2 += v*v;
    }
    s1 += __shfl_xor(s1, 16); s1 += __shfl_xor(s1, 32);
    s2 += __shfl_xor(s2, 16); s2 += __shfl_xor(s2, 32);
    if (l < 16) { sred[(wv*2+fn)*16 + lr] = s1; sred[128 + (wv*2+fn)*16 + lr] = s2; }
  }
  __syncthreads();
  if (t < 32) {
    float a = 0.f, b = 0.f;
#pragma unroll
    for (int w2 = 0; w2 < 4; ++w2) {
      a += sred[(w2*2 + (t >> 4))*16 + (t & 15)];
      b += sred[128 + (w2*2 + (t >> 4))*16 + (t & 15)];
    }
    pw1[(size_t)blockIdx.x*64 + t]      = a;
    pw1[(size_t)blockIdx.x*64 + 32 + t] = b;
  }
}

// ---------------------------------------------------------------- aggr (1 query/block, proven)
__launch_bounds__(256)
__global__ void aggr_k(const u16* __restrict__ w1, const float* sw1,
                       const float* gw2, const float* bw2,
                       const float* __restrict__ Ww2, const float* bww2,
                       const u16* __restrict__ xv,
                       const float* __restrict__ p, const int* __restrict__ idx,
                       const float* Wp1, const float* bp1, const float* gp, const float* bpp,
                       const float* sp, const float* __restrict__ Wp2, const float* bp2,
                       u16* __restrict__ y) {
  __shared__ float lw1[16][32];
  __shared__ float lW2[32][32];
  __shared__ float sw2[16][33];
  __shared__ float prv[16][4];
  __shared__ int   jidx[16];
  int i = blockIdx.x, t = threadIdx.x;
  for (int e = t; e < 1024; e += 256) lW2[e >> 5][e & 31] = Ww2[e];
  for (int e = t; e < 512; e += 256) {
    int c32 = e & 31;
    float v = b2f(w1[(size_t)i*512 + e]);
    v = fmaxf(bn_ap(v, sw1, 32, c32, INV_NK, gw2[c32], bw2[c32]), 0.0f);
    lw1[e >> 5][c32] = v;
  }
  if (t < 16) jidx[t] = idx[i*16 + t] & 8191;
  __syncthreads();
  if (t < 16) {
    float o3[3];
    comp_prv(p, i, jidx[t], Wp1, bp1, gp, bpp, sp, o3);
    prv[t][0] = o3[0]; prv[t][1] = o3[1]; prv[t][2] = o3[2];
  }
  for (int e = t; e < 512; e += 256) {
    int k = e >> 5, c32 = e & 31;
    float a = bww2[c32];
#pragma unroll
    for (int j = 0; j < 32; ++j) a += lw1[k][j] * lW2[j][c32];
    sw2[k][c32] = a;
  }
  __syncthreads();
  if (t < 32) {
    float mx = -3.0e38f;
#pragma unroll
    for (int k = 0; k < 16; ++k) mx = fmaxf(mx, sw2[k][t]);
    float s = 0.f;
#pragma unroll
    for (int k = 0; k < 16; ++k) { float e2 = expf(sw2[k][t] - mx); sw2[k][t] = e2; s += e2; }
    float r = 1.0f / s;
#pragma unroll
    for (int k = 0; k < 16; ++k) sw2[k][t] *= r;
  }
  __syncthreads();
  int c = t;
  float wp0 = Wp2[c], wp1v = Wp2[256+c], wp2v = Wp2[512+c];
  float bbv = bp2[c];
  int c32 = c & 31;
  float acc = 0.f;
#pragma unroll
  for (int k = 0; k < 16; ++k) {
    int j = jidx[k];
    float pr = prv[k][0]*wp0 + prv[k][1]*wp1v + prv[k][2]*wp2v + bbv;
    float xvv = b2f(xv[(size_t)j*256 + c]);
    acc += (xvv + pr) * sw2[k][c32];
  }
  y[(size_t)i*256 + c] = f2b(acc);
}

// ---------------------------------------------------------------- epilogue (bf16 in)
__launch_bounds__(256)
__global__ void final_k(const u16* __restrict__ t0, const float* s0,
                        const float* g0, const float* b0,
                        const u16* __restrict__ t3, const float* s3,
                        const float* g3, const float* b3,
                        float* __restrict__ out) {
  int i = blockIdx.x, c = threadIdx.x;
  size_t off = (size_t)i*256 + c;
  float h0 = fmaxf(bn_ap(b2f(t0[off]), s0, 256, c, INV_N, g0[c], b0[c]), 0.0f);
  float v3 = bn_ap(b2f(t3[off]), s3, 256, c, INV_N, g3[c], b3[c]);
  out[24576 + off] = fmaxf(v3 + h0, 0.0f);
}

// ---------------------------------------------------------------- launch
extern "C" void kernel_launch(void* const* d_in, const int* in_sizes, int n_in,
                              void* d_out, int out_size, void* d_ws, size_t ws_size,
                              hipStream_t stream) {
  (void)in_sizes; (void)n_in; (void)out_size; (void)ws_size;
  const float* p    = (const float*)d_in[0];
  const float* x    = (const float*)d_in[1];
  const int*   o    = (const int*)  d_in[2];
  const float* W_pa = (const float*)d_in[3];
  const float* g_pa = (const float*)d_in[4];
  const float* b_pa = (const float*)d_in[5];
  const float* W1   = (const float*)d_in[6];
  const float* g1   = (const float*)d_in[7];
  const float* b1   = (const float*)d_in[8];
  const float* Wq   = (const float*)d_in[9];
  const float* bq   = (const float*)d_in[10];
  const float* Wk   = (const float*)d_in[11];
  const float* bk   = (const float*)d_in[12];
  const float* Wv   = (const float*)d_in[13];
  const float* bv   = (const float*)d_in[14];
  const float* Wp1  = (const float*)d_in[15];
  const float* bp1  = (const float*)d_in[16];
  const float* gp   = (const float*)d_in[17];
  const float* bpp  = (const float*)d_in[18];
  const float* Wp2  = (const float*)d_in[19];
  const float* bp2  = (const float*)d_in[20];
  const float* gw1  = (const float*)d_in[21];
  const float* bw1  = (const float*)d_in[22];
  const float* Ww1  = (const float*)d_in[23];
  const float* bww1 = (const float*)d_in[24];
  const float* gw2  = (const float*)d_in[25];
  const float* bw2  = (const float*)d_in[26];
  const float* Ww2  = (const float*)d_in[27];
  const float* bww2 = (const float*)d_in[28];
  const float* g2   = (const float*)d_in[29];
  const float* b2   = (const float*)d_in[30];
  const float* W3   = (const float*)d_in[31];
  const float* g3   = (const float*)d_in[32];
  const float* b3   = (const float*)d_in[33];

  // workspace layout (~34 MB)
  char* ws = (char*)d_ws;
  u16*   t0  = (u16*)  (ws + 0);          // [8192,256] bf16 (live til final_k)
  u16*   t1  = (u16*)  (ws + 4194304);    // [8192,256] bf16 (later: y)
  u16*   xq  = (u16*)  (ws + 8388608);    // [8192,256] bf16 (later: t3)
  u16*   xk  = (u16*)  (ws + 12582912);   // [8192,256] bf16
  u16*   xv  = (u16*)  (ws + 16777216);   // [8192,256] bf16
  u16*   w1  = (u16*)  (ws + 20971520);   // [131072,32] bf16 (8 MB)
  int*   idx = (int*)  (ws + 29360128);   // [8192,16] i32
  float* st  = (float*)(ws + 29884416);   // stats block (16 KB)
  u16*   Ww1t= (u16*)  (ws + 29900800);   // [32][256] bf16 (16 KB)
  float* pw1 = (float*)(ws + 30408704);   // [2048][64] partials (512 KB)
  float* pws = (float*)(ws + 30932992);   // [1024][512] partials (2 MB)
  float* psy = (float*)(ws + 33030144);   // [256][512] partials (512 KB)
  u16*   y   = t1;                        // aggr output (t1 dead after qkv)
  u16*   t3  = xq;                        // aliases xq (dead after w1 stage)
  float4* pp = (float4*)(ws + 20971520);  // aliases w1 (knn finishes first)
  // st offsets: s0=0, s1=512, sw=1024, sy=1536, s3=2048, sw1=2560, sp=2624

  prep_k<<<96, 256, 0, stream>>>(p, o, Ww1, pp, Ww1t, st, (float*)d_out);

  gemmknn_k<<<2560, 256, 20480, stream>>>(x, W_pa, t0, st + 0, pp, idx);

  gemmpr_k<<<640, 256, 20480, stream>>>(t0, st + 0, g_pa, b_pa, W1, t1, st + 512,
                                        p, idx, Wp1, bp1, st + 2624);

  qkv_k<<<dim3(128, 4), 256, 0, stream>>>(
      t1, st + 512, g1, b1, Wq, bq, Wk, bk, Wv, bv, xq, xk, xv);

  wstats_k<<<1024, 256, 0, stream>>>(xk, xq, p, idx, Wp1, bp1, gp, bpp,
                                     st + 2624, Wp2, bp2, pws);
  red_k<1024, 4><<<32, 256, 0, stream>>>(pws, st + 1024, 512);

  w1gemm_k<<<2048, 256, 0, stream>>>(xk, xq, p, idx, Wp1, bp1, gp, bpp,
                                     st + 2624, Wp2, bp2, st + 1024,
                                     gw1, bw1, Ww1t, bww1, w1, pw1);
  red_k<2048, 16><<<16, 256, 0, stream>>>(pw1, st + 2560, 64);

  aggr_k<<<8192, 256, 0, stream>>>(w1, st + 2560, gw2, bw2, Ww2, bww2, xv,
                                   p, idx, Wp1, bp1, gp, bpp, st + 2624,
                                   Wp2, bp2, y);
  stats256_k<<<256, 256, 0, stream>>>(y, psy);
  red_k<256, 2><<<16, 256, 0, stream>>>(psy, st + 1536, 512);

  mfgemm_k<u16, u16, true, true><<<dim3(128, 4), 256, 20480, stream>>>(
      y, st + 1536, g2, b2, INV_N, W3, t3, st + 2048, 256, 256);

  final_k<<<8192, 256, 0, stream>>>(t0, st + 0, g_pa, b_pa,
                                    t3, st + 2048, g3, b3, (float*)d_out);
}